// Round 7
// baseline (438.318 us; speedup 1.0000x reference)
//
// Round 7: kNN Q=2 queries/wave + single-residency-round grids (1250 blocks);
// prop Q=2; fused counts-zero into pos4 and indegree-count into kNN phase 2
// (drops count_kernel + 2 memsets). knn was 133us @ 65% occupancy (2-round tail).
#include <hip/hip_runtime.h>
#include <hip/hip_bf16.h>
#include <cstdint>
#include <cstddef>

#define N_NODES 10000
#define KNN_K 20
#define NEDGE (N_NODES * KNN_K)
#define NBATCH 157                 // ceil(10000/64)
#define POS4_PAD 10048             // 157*64

using bf16x8 = __attribute__((ext_vector_type(8))) short;
using f32x4  = __attribute__((ext_vector_type(4))) float;

__device__ __forceinline__ float bf_lo(unsigned int u) {
  union { unsigned int i; float f; } c; c.i = u << 16; return c.f;
}
__device__ __forceinline__ float bf_hi(unsigned int u) {
  union { unsigned int i; float f; } c; c.i = u & 0xFFFF0000u; return c.f;
}
__device__ __forceinline__ unsigned short f2bf(float f) {
  union { float f; unsigned int i; } c; c.f = f;
  unsigned int u = c.i;
  u += 0x7FFFu + ((u >> 16) & 1u);   // RNE
  return (unsigned short)(u >> 16);
}

__device__ __forceinline__ void gll16(const void* g, void* l) {
  __builtin_amdgcn_global_load_lds(
      (const __attribute__((address_space(1))) unsigned int*)g,
      (__attribute__((address_space(3))) unsigned int*)l,
      16, 0, 0);
}

// ---------------- transpose f32 [srows][scols] -> bf16 dst[col][dcol0 + row] ----------------
__global__ __launch_bounds__(256) void transpose_f32_bf16(
    const float* __restrict__ src0, unsigned short* __restrict__ dst,
    int srows, int scols, int dstride, size_t slice_elems, int dcol_per_slice)
{
  __shared__ float lds[64 * 65];
  const int z = blockIdx.z;
  const float* src = src0 + (size_t)z * slice_elems;
  const int dcol0 = z * dcol_per_slice;
  const int c0 = blockIdx.x * 64;
  const int r0 = blockIdx.y * 64;
  const int tid = threadIdx.x;
#pragma unroll
  for (int q = 0; q < 4; ++q) {
    int unit = q * 256 + tid;            // 1024 float4 units
    int rr = unit >> 4;                  // 0..63
    int cu = unit & 15;                  // 0..15
    int r = r0 + rr, c = c0 + cu * 4;
    float4 v = make_float4(0.f, 0.f, 0.f, 0.f);
    if (r < srows && c + 3 < scols) v = *(const float4*)&src[(size_t)r * scols + c];
    lds[rr * 65 + cu * 4 + 0] = v.x;
    lds[rr * 65 + cu * 4 + 1] = v.y;
    lds[rr * 65 + cu * 4 + 2] = v.z;
    lds[rr * 65 + cu * 4 + 3] = v.w;
  }
  __syncthreads();
#pragma unroll
  for (int q = 0; q < 2; ++q) {
    int unit = q * 256 + tid;            // 512 units of 8 bf16
    int cl = unit >> 3;                  // src col within tile (= dst row)
    int ru = unit & 7;
    int c = c0 + cl;
    if (c < scols) {
      unsigned short tmp[8];
#pragma unroll
      for (int j = 0; j < 8; ++j) tmp[j] = f2bf(lds[(ru * 8 + j) * 65 + cl]);
      uint4 o;
      o.x = (unsigned int)tmp[0] | ((unsigned int)tmp[1] << 16);
      o.y = (unsigned int)tmp[2] | ((unsigned int)tmp[3] << 16);
      o.z = (unsigned int)tmp[4] | ((unsigned int)tmp[5] << 16);
      o.w = (unsigned int)tmp[6] | ((unsigned int)tmp[7] << 16);
      *(uint4*)&dst[(size_t)c * dstride + dcol0 + r0 + ru * 8] = o;
    }
  }
}

// ---------------- pos4: pack (x,y,z,|p|^2); pad rows w=+INF; zero counts/cursor ----------------
__global__ __launch_bounds__(256) void pos4_kernel(
    const float* __restrict__ pos, float4* __restrict__ pos4,
    int* __restrict__ counts, int* __restrict__ cursor)
{
  int c = blockIdx.x * 256 + threadIdx.x;      // grid 40 -> 10240 threads
  if (c < POS4_PAD) {
    float4 v;
    if (c < N_NODES) {
      float x = pos[c * 3 + 0], y = pos[c * 3 + 1], z = pos[c * 3 + 2];
      v = make_float4(x, y, z, x * x + y * y + z * z);
    } else {
      v = make_float4(0.f, 0.f, 0.f, __builtin_inff());   // d -> +INF
    }
    pos4[c] = v;
  }
  if (c < N_NODES) { counts[c] = 0; cursor[c] = 0; }
}

// identical expression in both phases -> bit-identical distances
__device__ __forceinline__ float knn_dist(float4 pi, float4 s) {
  float dot = fmaf(pi.x, s.x, fmaf(pi.y, s.y, pi.z * s.z));
  return fmaf(-2.0f, dot, pi.w + s.w);
}

__device__ __forceinline__ void insert8(float r[8], float k) {
  // r ascending; r_j = median(k, r_{j-1}, r_j) == min(r_j, max(r_{j-1}, k))
  asm("v_med3_f32 %0, %1, %2, %3" : "=v"(r[7]) : "v"(k), "v"(r[6]), "v"(r[7]));
  asm("v_med3_f32 %0, %1, %2, %3" : "=v"(r[6]) : "v"(k), "v"(r[5]), "v"(r[6]));
  asm("v_med3_f32 %0, %1, %2, %3" : "=v"(r[5]) : "v"(k), "v"(r[4]), "v"(r[5]));
  asm("v_med3_f32 %0, %1, %2, %3" : "=v"(r[4]) : "v"(k), "v"(r[3]), "v"(r[4]));
  asm("v_med3_f32 %0, %1, %2, %3" : "=v"(r[3]) : "v"(k), "v"(r[2]), "v"(r[3]));
  asm("v_med3_f32 %0, %1, %2, %3" : "=v"(r[2]) : "v"(k), "v"(r[1]), "v"(r[2]));
  asm("v_med3_f32 %0, %1, %2, %3" : "=v"(r[1]) : "v"(k), "v"(r[0]), "v"(r[1]));
  r[0] = fminf(r[0], k);
}

__device__ __forceinline__ float merge_tau20(float r[8], int lane) {
  const float INF = __builtin_inff();
  float tau = INF;
#pragma unroll
  for (int t = 0; t < KNN_K; ++t) {
    float m = r[0];
    m = fminf(m, __shfl_xor(m, 1));
    m = fminf(m, __shfl_xor(m, 2));
    m = fminf(m, __shfl_xor(m, 4));
    m = fminf(m, __shfl_xor(m, 8));
    m = fminf(m, __shfl_xor(m, 16));
    m = fminf(m, __shfl_xor(m, 32));
    unsigned long long who = __ballot(r[0] == m);
    int srcl = __ffsll(who) - 1;                  // pop exactly one holder
    if (lane == srcl) {
#pragma unroll
      for (int z = 0; z < 7; ++z) r[z] = r[z + 1];
      r[7] = INF;
    }
    tau = m;
  }
  return tau;                                      // exact 20th smallest
}

__device__ __forceinline__ void emit_hits(
    int i, bool valid, float d, float tau, int cid, int lane, int& cnt,
    int* __restrict__ knn_out, int* __restrict__ counts)
{
  unsigned long long less = __ballot(valid && d < tau);
  unsigned long long eq   = __ballot(valid && d == tau);
  if (less) {
    if (valid && d < tau) {
      int pos = cnt + (int)__popcll(less & ((1ull << lane) - 1ull));
      if (pos < KNN_K) {                           // #{d<tau} <= 19 guaranteed
        knn_out[i * KNN_K + pos] = cid;
        atomicAdd(&counts[cid], 1);
      }
    }
    cnt += (int)__popcll(less);
  }
  if (eq && cnt < KNN_K) {
    if (valid && d == tau) {
      int pos = cnt + (int)__popcll(eq & ((1ull << lane) - 1ull));
      if (pos < KNN_K) {
        knn_out[i * KNN_K + pos] = cid;
        atomicAdd(&counts[cid], 1);
      }
    }
    cnt = min(KNN_K, cnt + (int)__popcll(eq));
  }
}

// ---------------- kNN: 2 queries/wave; f32 top-8 via med3; tau; index recovery ----------------
__global__ __launch_bounds__(256) void knn_kernel(
    const float4* __restrict__ pos4, int* __restrict__ knn_out,
    int* __restrict__ counts)
{
  const int lane = threadIdx.x & 63, wave = threadIdx.x >> 6;
  const int iq = blockIdx.x * 4 + wave;           // 0..4999
  const int i0 = iq * 2, i1 = iq * 2 + 1;
  const float4 p0 = pos4[i0];
  const float4 p1 = pos4[i1];
  const float INF = __builtin_inff();

  float ra[8], rb[8];
#pragma unroll
  for (int z = 0; z < 8; ++z) { ra[z] = INF; rb[z] = INF; }

  // phase 1: per-lane top-8 of distances for both queries (shared candidate load)
#pragma unroll 4
  for (int b = 0; b < NBATCH; ++b) {
    const int cid = b * 64 + lane;
    const float4 s = pos4[cid];
    float d0 = knn_dist(p0, s);                   // pad rows: +INF
    float d1 = knn_dist(p1, s);
    float k0 = (cid == i0) ? INF : d0;            // exclude self
    float k1 = (cid == i1) ? INF : d1;
    insert8(ra, k0);
    insert8(rb, k1);
  }

  const float tau0 = merge_tau20(ra, lane);
  const float tau1 = merge_tau20(rb, lane);

  // phase 2: recover indices — all {d < tau}, then {d == tau} lowest-index first
  int cnt0 = 0, cnt1 = 0;
  for (int b = 0; b < NBATCH; ++b) {
    const int cid = b * 64 + lane;
    const float4 s = pos4[cid];
    float d0 = knn_dist(p0, s);
    float d1 = knn_dist(p1, s);
    emit_hits(i0, cid != i0, d0, tau0, cid, lane, cnt0, knn_out, counts);
    emit_hits(i1, cid != i1, d1, tau1, cid, lane, cnt1, knn_out, counts);
  }
}

// ---------------- reverse-CSR build ----------------
__global__ __launch_bounds__(256) void scan_kernel(
    const int* __restrict__ counts, int* __restrict__ rptr)
{
  __shared__ int part[256];
  const int tid = threadIdx.x;
  const int base = tid * 40;                       // 256*40 = 10240 >= 10000
  int s = 0;
  for (int q = 0; q < 40; ++q) { int idx = base + q; if (idx < N_NODES) s += counts[idx]; }
  part[tid] = s;
  __syncthreads();
  for (int off = 1; off < 256; off <<= 1) {
    int add = (tid >= off) ? part[tid - off] : 0;
    __syncthreads();
    part[tid] += add;
    __syncthreads();
  }
  int run = part[tid] - s;                         // exclusive offset
  for (int q = 0; q < 40; ++q) {
    int idx = base + q;
    if (idx < N_NODES) { rptr[idx] = run; run += counts[idx]; }
  }
  if (tid == 255) rptr[N_NODES] = run;
}

__global__ __launch_bounds__(256) void fill_kernel(
    const int* __restrict__ knn, const int* __restrict__ rptr,
    int* __restrict__ cursor, int* __restrict__ rsrc)
{
  int e = blockIdx.x * 256 + threadIdx.x;
  if (e < NEDGE) {
    int j = knn[e];
    int i = e / KNN_K;
    int p = atomicAdd(&cursor[j], 1);
    rsrc[rptr[j] + p] = i;
  }
}

// sort each reverse-adjacency list -> deterministic gather order
__global__ __launch_bounds__(256) void sort_kernel(
    const int* __restrict__ rptr, int* __restrict__ rsrc)
{
  int j = blockIdx.x * 256 + threadIdx.x;
  if (j < N_NODES) {
    int s0 = rptr[j], s1 = rptr[j + 1];
    for (int a = s0 + 1; a < s1; ++a) {
      int v = rsrc[a];
      int b = a - 1;
      while (b >= s0 && rsrc[b] > v) { rsrc[b + 1] = rsrc[b]; --b; }
      rsrc[b + 1] = v;
    }
  }
}

// ---------------- prop: out[j] = scale2 * sum_{i in rev(j)} t[i]  - prev[j] ----------------
__global__ __launch_bounds__(256) void prop_kernel(
    const unsigned short* __restrict__ tin, const unsigned short* __restrict__ tprev,
    unsigned short* __restrict__ tout, const int* __restrict__ rptr,
    const int* __restrict__ rsrc, float scale2)
{
  const int wave = threadIdx.x >> 6, lane = threadIdx.x & 63;
  const int jq = blockIdx.x * 4 + wave;            // 0..4999
  const size_t coff = (size_t)lane * 8;
#pragma unroll
  for (int h = 0; h < 2; ++h) {
    const int j = jq + h * 5000;
    const int s0 = rptr[j], s1 = rptr[j + 1];
    float acc[8] = {0.f, 0.f, 0.f, 0.f, 0.f, 0.f, 0.f, 0.f};
    for (int s = s0; s < s1; ++s) {
      int src = rsrc[s];
      uint4 v = *(const uint4*)&tin[(size_t)src * 512 + coff];
      acc[0] += bf_lo(v.x); acc[1] += bf_hi(v.x);
      acc[2] += bf_lo(v.y); acc[3] += bf_hi(v.y);
      acc[4] += bf_lo(v.z); acc[5] += bf_hi(v.z);
      acc[6] += bf_lo(v.w); acc[7] += bf_hi(v.w);
    }
    float pv[8] = {0.f, 0.f, 0.f, 0.f, 0.f, 0.f, 0.f, 0.f};
    if (tprev != nullptr) {
      uint4 p = *(const uint4*)&tprev[(size_t)j * 512 + coff];
      pv[0] = bf_lo(p.x); pv[1] = bf_hi(p.x);
      pv[2] = bf_lo(p.y); pv[3] = bf_hi(p.y);
      pv[4] = bf_lo(p.z); pv[5] = bf_hi(p.z);
      pv[6] = bf_lo(p.w); pv[7] = bf_hi(p.w);
    }
    unsigned short o16[8];
#pragma unroll
    for (int q = 0; q < 8; ++q) o16[q] = f2bf(scale2 * acc[q] - pv[q]);
    uint4 o;
    o.x = (unsigned int)o16[0] | ((unsigned int)o16[1] << 16);
    o.y = (unsigned int)o16[2] | ((unsigned int)o16[3] << 16);
    o.z = (unsigned int)o16[4] | ((unsigned int)o16[5] << 16);
    o.w = (unsigned int)o16[6] | ((unsigned int)o16[7] << 16);
    *(uint4*)&tout[(size_t)j * 512 + coff] = o;
  }
}

// ---------------- GEMM: C[o][n] = sum_kc A[n][kc] * B[kc][o] + bias[o] ----------------
// A = TxAll bf16: 5 blocks of [10000][512] (+pad). B^T = thetabT bf16 [512][2560].
__global__ __launch_bounds__(256) void gemm_kernel(
    const unsigned short* __restrict__ A,
    const unsigned short* __restrict__ Bt,
    const float* __restrict__ bias,
    float* __restrict__ C)
{
  __shared__ __align__(16) char smem[64 * 132 * 4];   // 33792B: tiles(32KB) / epilogue(33KB)
  unsigned short* As = (unsigned short*)smem;         // [128][64] bf16
  unsigned short* Bs = As + 128 * 64;                 // [128 o][64 k] bf16
  float* eps = (float*)smem;                          // [64 o][132] f32

  const int tid = threadIdx.x;
  const int wave = tid >> 6, lane = tid & 63;
  const int l15 = lane & 15, hi = lane >> 4;
  const int wr = wave >> 1, wc = wave & 1;
  const int n0 = blockIdx.x * 128;
  const int o0 = blockIdx.y * 128;

  f32x4 acc[4][4];
#pragma unroll
  for (int a = 0; a < 4; ++a)
#pragma unroll
    for (int b = 0; b < 4; ++b) acc[a][b] = (f32x4){0.f, 0.f, 0.f, 0.f};

  for (int kt = 0; kt < 40; ++kt) {
    const int k0 = kt * 64;
    const int ko = k0 >> 9;
    const int c0 = k0 & 511;
    const unsigned short* Ab = A + (size_t)ko * ((size_t)N_NODES * 512);
#pragma unroll
    for (int q = 0; q < 4; ++q) {
      int idx = (wave * 4 + q) * 64 + lane;     // 16B unit id, 0..1023
      int r = idx >> 3, u = idx & 7;
      gll16(Ab + (size_t)(n0 + r) * 512 + c0 + u * 8, As + (size_t)(wave * 4 + q) * 512);
    }
#pragma unroll
    for (int q = 0; q < 4; ++q) {
      int idx = (wave * 4 + q) * 64 + lane;
      int r = idx >> 3, u = idx & 7;
      gll16(Bt + (size_t)(o0 + r) * 2560 + k0 + u * 8, Bs + (size_t)(wave * 4 + q) * 512);
    }
    __syncthreads();
#pragma unroll
    for (int kk = 0; kk < 2; ++kk) {
      bf16x8 af[4], bfr[4];
#pragma unroll
      for (int mi = 0; mi < 4; ++mi)
        af[mi] = *(const bf16x8*)(As + ((wr * 64 + mi * 16 + l15) * 64 + kk * 32 + hi * 8));
#pragma unroll
      for (int ni = 0; ni < 4; ++ni)
        bfr[ni] = *(const bf16x8*)(Bs + ((wc * 64 + ni * 16 + l15) * 64 + kk * 32 + hi * 8));
#pragma unroll
      for (int mi = 0; mi < 4; ++mi)
#pragma unroll
        for (int ni = 0; ni < 4; ++ni)
          acc[mi][ni] = __builtin_amdgcn_mfma_f32_16x16x32_bf16(af[mi], bfr[ni], acc[mi][ni], 0, 0, 0);
    }
    __syncthreads();
  }

  // epilogue: LDS-transposed coalesced store of C[o][n] + bias
#pragma unroll
  for (int h = 0; h < 2; ++h) {
    __syncthreads();
    if (wc == h) {
#pragma unroll
      for (int mi = 0; mi < 4; ++mi)
#pragma unroll
        for (int ni = 0; ni < 4; ++ni) {
          int o_l = ni * 16 + l15;                   // 0..63 within half
          int nb = wr * 64 + mi * 16 + hi * 4;       // 0..124, x4 aligned
          *(f32x4*)&eps[o_l * 132 + nb] = acc[mi][ni];
        }
    }
    __syncthreads();
#pragma unroll
    for (int q = 0; q < 8; ++q) {
      int unit = q * 256 + tid;                      // 2048 float4 units
      int o_l = unit >> 5, nu = unit & 31;
      int n = n0 + nu * 4;
      if (n < N_NODES) {
        int o = o0 + h * 64 + o_l;
        f32x4 v = *(const f32x4*)&eps[o_l * 132 + nu * 4];
        float bo = bias[o];
        v = v + bo;
        *(f32x4*)&C[(size_t)o * N_NODES + n] = v;
      }
    }
  }
}

extern "C" void kernel_launch(void* const* d_in, const int* in_sizes, int n_in,
                              void* d_out, int out_size, void* d_ws, size_t ws_size,
                              hipStream_t stream)
{
  const float* x        = (const float*)d_in[0];   // [512][10000]
  const float* position = (const float*)d_in[1];   // [10000][3]
  const float* theta    = (const float*)d_in[2];   // [5][512][512]
  const float* bias     = (const float*)d_in[3];   // [512]

  char* ws = (char*)d_ws;
  size_t off = 0;
  auto alloc = [&](size_t bytes) -> void* {
    void* p = ws + off;
    off = (off + bytes + 255) & ~(size_t)255;
    return p;
  };
  unsigned short* TxAll   = (unsigned short*)alloc(5ull * N_NODES * 512 * 2 + 131072); // +128-row pad
  unsigned short* thetabT = (unsigned short*)alloc(512ull * 2560 * 2);
  float4* pos4 = (float4*)alloc((size_t)POS4_PAD * 16);
  int* knn    = (int*)alloc((size_t)NEDGE * 4);
  int* rptr   = (int*)alloc((size_t)(N_NODES + 1) * 4);
  int* counts = (int*)alloc((size_t)N_NODES * 4);
  int* cursor = (int*)alloc((size_t)N_NODES * 4);
  int* rsrc   = (int*)alloc((size_t)NEDGE * 4);
  if (ws_size < off) return;   // insufficient scratch

  // theta [5][512][512] -> thetabT [o=512][kc=2560]
  transpose_f32_bf16<<<dim3(8, 8, 5), 256, 0, stream>>>(
      theta, thetabT, 512, 512, 2560, (size_t)512 * 512, 512);
  // x [512][10000] -> Tx0 [10000][512]
  transpose_f32_bf16<<<dim3(157, 8, 1), 256, 0, stream>>>(
      x, TxAll, 512, N_NODES, 512, 0, 0);

  pos4_kernel<<<40, 256, 0, stream>>>(position, pos4, counts, cursor);
  knn_kernel<<<1250, 256, 0, stream>>>(pos4, knn, counts);

  scan_kernel<<<1, 256, 0, stream>>>(counts, rptr);
  fill_kernel<<<(NEDGE + 255) / 256, 256, 0, stream>>>(knn, rptr, cursor, rsrc);
  sort_kernel<<<(N_NODES + 255) / 256, 256, 0, stream>>>(rptr, rsrc);

  unsigned short* Tx0 = TxAll;
  unsigned short* Tx1 = TxAll + 1ull * N_NODES * 512;
  unsigned short* Tx2 = TxAll + 2ull * N_NODES * 512;
  unsigned short* Tx3 = TxAll + 3ull * N_NODES * 512;
  unsigned short* Tx4 = TxAll + 4ull * N_NODES * 512;

  // Tx1 = prop(Tx0) = -0.05*sum ; Tx_k = 2*prop(Tx_{k-1}) - Tx_{k-2} = -0.10*sum - prev
  prop_kernel<<<1250, 256, 0, stream>>>(Tx0, nullptr, Tx1, rptr, rsrc, -0.05f);
  prop_kernel<<<1250, 256, 0, stream>>>(Tx1, Tx0,     Tx2, rptr, rsrc, -0.10f);
  prop_kernel<<<1250, 256, 0, stream>>>(Tx2, Tx1,     Tx3, rptr, rsrc, -0.10f);
  prop_kernel<<<1250, 256, 0, stream>>>(Tx3, Tx2,     Tx4, rptr, rsrc, -0.10f);

  gemm_kernel<<<dim3(79, 4), 256, 0, stream>>>(TxAll, thetabT, bias, (float*)d_out);
}

// Round 8
// 390.764 us; speedup vs baseline: 1.1217x; 1.1217x over previous
//
// Round 8: revert kNN to round-6 exact (133us known-good; Q=2 regressed to 140
// via TLP loss + atomics). Rewrite prop_kernel for memory-level parallelism:
// shfl-broadcast rsrc prefetch + 4-way unrolled independent gather chains.
#include <hip/hip_runtime.h>
#include <hip/hip_bf16.h>
#include <cstdint>
#include <cstddef>

#define N_NODES 10000
#define KNN_K 20
#define NEDGE (N_NODES * KNN_K)
#define NBATCH 157                 // ceil(10000/64)
#define POS4_PAD 10048             // 157*64

using bf16x8 = __attribute__((ext_vector_type(8))) short;
using f32x4  = __attribute__((ext_vector_type(4))) float;

__device__ __forceinline__ float bf_lo(unsigned int u) {
  union { unsigned int i; float f; } c; c.i = u << 16; return c.f;
}
__device__ __forceinline__ float bf_hi(unsigned int u) {
  union { unsigned int i; float f; } c; c.i = u & 0xFFFF0000u; return c.f;
}
__device__ __forceinline__ unsigned short f2bf(float f) {
  union { float f; unsigned int i; } c; c.f = f;
  unsigned int u = c.i;
  u += 0x7FFFu + ((u >> 16) & 1u);   // RNE
  return (unsigned short)(u >> 16);
}

__device__ __forceinline__ void gll16(const void* g, void* l) {
  __builtin_amdgcn_global_load_lds(
      (const __attribute__((address_space(1))) unsigned int*)g,
      (__attribute__((address_space(3))) unsigned int*)l,
      16, 0, 0);
}

// ---------------- transpose f32 [srows][scols] -> bf16 dst[col][dcol0 + row] ----------------
__global__ __launch_bounds__(256) void transpose_f32_bf16(
    const float* __restrict__ src0, unsigned short* __restrict__ dst,
    int srows, int scols, int dstride, size_t slice_elems, int dcol_per_slice)
{
  __shared__ float lds[64 * 65];
  const int z = blockIdx.z;
  const float* src = src0 + (size_t)z * slice_elems;
  const int dcol0 = z * dcol_per_slice;
  const int c0 = blockIdx.x * 64;
  const int r0 = blockIdx.y * 64;
  const int tid = threadIdx.x;
#pragma unroll
  for (int q = 0; q < 4; ++q) {
    int unit = q * 256 + tid;            // 1024 float4 units
    int rr = unit >> 4;                  // 0..63
    int cu = unit & 15;                  // 0..15
    int r = r0 + rr, c = c0 + cu * 4;
    float4 v = make_float4(0.f, 0.f, 0.f, 0.f);
    if (r < srows && c + 3 < scols) v = *(const float4*)&src[(size_t)r * scols + c];
    lds[rr * 65 + cu * 4 + 0] = v.x;
    lds[rr * 65 + cu * 4 + 1] = v.y;
    lds[rr * 65 + cu * 4 + 2] = v.z;
    lds[rr * 65 + cu * 4 + 3] = v.w;
  }
  __syncthreads();
#pragma unroll
  for (int q = 0; q < 2; ++q) {
    int unit = q * 256 + tid;            // 512 units of 8 bf16
    int cl = unit >> 3;                  // src col within tile (= dst row)
    int ru = unit & 7;
    int c = c0 + cl;
    if (c < scols) {
      unsigned short tmp[8];
#pragma unroll
      for (int j = 0; j < 8; ++j) tmp[j] = f2bf(lds[(ru * 8 + j) * 65 + cl]);
      uint4 o;
      o.x = (unsigned int)tmp[0] | ((unsigned int)tmp[1] << 16);
      o.y = (unsigned int)tmp[2] | ((unsigned int)tmp[3] << 16);
      o.z = (unsigned int)tmp[4] | ((unsigned int)tmp[5] << 16);
      o.w = (unsigned int)tmp[6] | ((unsigned int)tmp[7] << 16);
      *(uint4*)&dst[(size_t)c * dstride + dcol0 + r0 + ru * 8] = o;
    }
  }
}

// ---------------- pos4: pack (x,y,z,|p|^2); pad rows w=+INF; zero counts/cursor ----------------
__global__ __launch_bounds__(256) void pos4_kernel(
    const float* __restrict__ pos, float4* __restrict__ pos4,
    int* __restrict__ counts, int* __restrict__ cursor)
{
  int c = blockIdx.x * 256 + threadIdx.x;      // grid 40 -> 10240 threads
  if (c < POS4_PAD) {
    float4 v;
    if (c < N_NODES) {
      float x = pos[c * 3 + 0], y = pos[c * 3 + 1], z = pos[c * 3 + 2];
      v = make_float4(x, y, z, x * x + y * y + z * z);
    } else {
      v = make_float4(0.f, 0.f, 0.f, __builtin_inff());   // d -> +INF
    }
    pos4[c] = v;
  }
  if (c < N_NODES) { counts[c] = 0; cursor[c] = 0; }
}

// identical expression in both phases -> bit-identical distances
__device__ __forceinline__ float knn_dist(float4 pi, float4 s) {
  float dot = fmaf(pi.x, s.x, fmaf(pi.y, s.y, pi.z * s.z));
  return fmaf(-2.0f, dot, pi.w + s.w);
}

// ---------------- kNN (round-6 exact): wave/node; f32 top-8 via med3; tau; recovery ----------------
__global__ __launch_bounds__(256) void knn_kernel(
    const float4* __restrict__ pos4, int* __restrict__ knn_out)
{
  const int lane = threadIdx.x & 63, wave = threadIdx.x >> 6;
  const int i = blockIdx.x * 4 + wave;
  const float4 pi = pos4[i];
  const float INF = __builtin_inff();

  float r0 = INF, r1 = INF, r2 = INF, r3 = INF;
  float r4 = INF, r5 = INF, r6 = INF, r7 = INF;

  // phase 1: per-lane top-8 of distances (branchless med3 insert network)
#pragma unroll 4
  for (int b = 0; b < NBATCH; ++b) {
    const int cid = b * 64 + lane;
    const float4 s = pos4[cid];
    float d = knn_dist(pi, s);                    // pad rows: +INF
    float k = (cid == i) ? INF : d;               // exclude self
    asm("v_med3_f32 %0, %1, %2, %3" : "=v"(r7) : "v"(k), "v"(r6), "v"(r7));
    asm("v_med3_f32 %0, %1, %2, %3" : "=v"(r6) : "v"(k), "v"(r5), "v"(r6));
    asm("v_med3_f32 %0, %1, %2, %3" : "=v"(r5) : "v"(k), "v"(r4), "v"(r5));
    asm("v_med3_f32 %0, %1, %2, %3" : "=v"(r4) : "v"(k), "v"(r3), "v"(r4));
    asm("v_med3_f32 %0, %1, %2, %3" : "=v"(r3) : "v"(k), "v"(r2), "v"(r3));
    asm("v_med3_f32 %0, %1, %2, %3" : "=v"(r2) : "v"(k), "v"(r1), "v"(r2));
    asm("v_med3_f32 %0, %1, %2, %3" : "=v"(r1) : "v"(k), "v"(r0), "v"(r1));
    r0 = fminf(r0, k);
  }

  // merge: 20 duplicate-safe extract-min rounds -> tau = exact 20th smallest
  float tau = INF;
#pragma unroll
  for (int r = 0; r < KNN_K; ++r) {
    float m = r0;
    m = fminf(m, __shfl_xor(m, 1));
    m = fminf(m, __shfl_xor(m, 2));
    m = fminf(m, __shfl_xor(m, 4));
    m = fminf(m, __shfl_xor(m, 8));
    m = fminf(m, __shfl_xor(m, 16));
    m = fminf(m, __shfl_xor(m, 32));
    unsigned long long who = __ballot(r0 == m);
    int srcl = __ffsll(who) - 1;                  // pop exactly one holder
    if (lane == srcl) {
      r0 = r1; r1 = r2; r2 = r3; r3 = r4; r4 = r5; r5 = r6; r6 = r7; r7 = INF;
    }
    tau = m;                                       // after loop: 20th smallest
  }

  // phase 2: recover indices — all {d < tau}, then {d == tau} lowest-index first
  int cnt = 0;
  for (int b = 0; b < NBATCH; ++b) {
    const int cid = b * 64 + lane;
    const float4 s = pos4[cid];
    float d = knn_dist(pi, s);
    bool valid = (cid != i);                      // pad rows: d=INF, self-excluded
    unsigned long long less = __ballot(valid && d < tau);
    unsigned long long eq   = __ballot(valid && d == tau);
    if (less) {
      if (valid && d < tau) {
        int pos = cnt + (int)__popcll(less & ((1ull << lane) - 1ull));
        if (pos < KNN_K) knn_out[i * KNN_K + pos] = cid;
      }
      cnt += (int)__popcll(less);
    }
    if (eq && cnt < KNN_K) {
      if (valid && d == tau) {
        int pos = cnt + (int)__popcll(eq & ((1ull << lane) - 1ull));
        if (pos < KNN_K) knn_out[i * KNN_K + pos] = cid;
      }
      cnt = min(KNN_K, cnt + (int)__popcll(eq));
    }
  }
}

// ---------------- reverse-CSR build ----------------
__global__ __launch_bounds__(256) void count_kernel(
    const int* __restrict__ knn, int* __restrict__ counts)
{
  int e = blockIdx.x * 256 + threadIdx.x;
  if (e < NEDGE) atomicAdd(&counts[knn[e]], 1);
}

__global__ __launch_bounds__(256) void scan_kernel(
    const int* __restrict__ counts, int* __restrict__ rptr)
{
  __shared__ int part[256];
  const int tid = threadIdx.x;
  const int base = tid * 40;                       // 256*40 = 10240 >= 10000
  int s = 0;
  for (int q = 0; q < 40; ++q) { int idx = base + q; if (idx < N_NODES) s += counts[idx]; }
  part[tid] = s;
  __syncthreads();
  for (int off = 1; off < 256; off <<= 1) {
    int add = (tid >= off) ? part[tid - off] : 0;
    __syncthreads();
    part[tid] += add;
    __syncthreads();
  }
  int run = part[tid] - s;                         // exclusive offset
  for (int q = 0; q < 40; ++q) {
    int idx = base + q;
    if (idx < N_NODES) { rptr[idx] = run; run += counts[idx]; }
  }
  if (tid == 255) rptr[N_NODES] = run;
}

__global__ __launch_bounds__(256) void fill_kernel(
    const int* __restrict__ knn, const int* __restrict__ rptr,
    int* __restrict__ cursor, int* __restrict__ rsrc)
{
  int e = blockIdx.x * 256 + threadIdx.x;
  if (e < NEDGE) {
    int j = knn[e];
    int i = e / KNN_K;
    int p = atomicAdd(&cursor[j], 1);
    rsrc[rptr[j] + p] = i;
  }
}

// sort each reverse-adjacency list -> deterministic gather order
__global__ __launch_bounds__(256) void sort_kernel(
    const int* __restrict__ rptr, int* __restrict__ rsrc)
{
  int j = blockIdx.x * 256 + threadIdx.x;
  if (j < N_NODES) {
    int s0 = rptr[j], s1 = rptr[j + 1];
    for (int a = s0 + 1; a < s1; ++a) {
      int v = rsrc[a];
      int b = a - 1;
      while (b >= s0 && rsrc[b] > v) { rsrc[b + 1] = rsrc[b]; --b; }
      rsrc[b + 1] = v;
    }
  }
}

// ---------------- prop: out[j] = scale2 * sum_{i in rev(j)} t[i] - prev[j] ----------------
// MLP rewrite: shfl-broadcast rsrc prefetch + 4 independent gather/acc chains.
__global__ __launch_bounds__(256) void prop_kernel(
    const unsigned short* __restrict__ tin, const unsigned short* __restrict__ tprev,
    unsigned short* __restrict__ tout, const int* __restrict__ rptr,
    const int* __restrict__ rsrc, float scale2)
{
  const int wave = threadIdx.x >> 6, lane = threadIdx.x & 63;
  const int j = blockIdx.x * 4 + wave;             // 2500 blocks
  const int s0 = rptr[j], s1 = rptr[j + 1];
  const size_t coff = (size_t)lane * 8;

  float a0[8], a1[8], a2[8], a3[8];
#pragma unroll
  for (int q = 0; q < 8; ++q) { a0[q] = 0.f; a1[q] = 0.f; a2[q] = 0.f; a3[q] = 0.f; }

  for (int base = s0; base < s1; base += 64) {
    const int clen = min(64, s1 - base);
    int myidx = (base + lane < s1) ? rsrc[base + lane] : 0;
    int t = 0;
    for (; t + 4 <= clen; t += 4) {
      int i0 = __shfl(myidx, t);
      int i1 = __shfl(myidx, t + 1);
      int i2 = __shfl(myidx, t + 2);
      int i3 = __shfl(myidx, t + 3);
      uint4 v0 = *(const uint4*)&tin[(size_t)i0 * 512 + coff];
      uint4 v1 = *(const uint4*)&tin[(size_t)i1 * 512 + coff];
      uint4 v2 = *(const uint4*)&tin[(size_t)i2 * 512 + coff];
      uint4 v3 = *(const uint4*)&tin[(size_t)i3 * 512 + coff];
      a0[0] += bf_lo(v0.x); a0[1] += bf_hi(v0.x); a0[2] += bf_lo(v0.y); a0[3] += bf_hi(v0.y);
      a0[4] += bf_lo(v0.z); a0[5] += bf_hi(v0.z); a0[6] += bf_lo(v0.w); a0[7] += bf_hi(v0.w);
      a1[0] += bf_lo(v1.x); a1[1] += bf_hi(v1.x); a1[2] += bf_lo(v1.y); a1[3] += bf_hi(v1.y);
      a1[4] += bf_lo(v1.z); a1[5] += bf_hi(v1.z); a1[6] += bf_lo(v1.w); a1[7] += bf_hi(v1.w);
      a2[0] += bf_lo(v2.x); a2[1] += bf_hi(v2.x); a2[2] += bf_lo(v2.y); a2[3] += bf_hi(v2.y);
      a2[4] += bf_lo(v2.z); a2[5] += bf_hi(v2.z); a2[6] += bf_lo(v2.w); a2[7] += bf_hi(v2.w);
      a3[0] += bf_lo(v3.x); a3[1] += bf_hi(v3.x); a3[2] += bf_lo(v3.y); a3[3] += bf_hi(v3.y);
      a3[4] += bf_lo(v3.z); a3[5] += bf_hi(v3.z); a3[6] += bf_lo(v3.w); a3[7] += bf_hi(v3.w);
    }
    for (; t < clen; ++t) {
      int i0 = __shfl(myidx, t);
      uint4 v0 = *(const uint4*)&tin[(size_t)i0 * 512 + coff];
      a0[0] += bf_lo(v0.x); a0[1] += bf_hi(v0.x); a0[2] += bf_lo(v0.y); a0[3] += bf_hi(v0.y);
      a0[4] += bf_lo(v0.z); a0[5] += bf_hi(v0.z); a0[6] += bf_lo(v0.w); a0[7] += bf_hi(v0.w);
    }
  }

  float pv[8] = {0.f, 0.f, 0.f, 0.f, 0.f, 0.f, 0.f, 0.f};
  if (tprev != nullptr) {
    uint4 p = *(const uint4*)&tprev[(size_t)j * 512 + coff];
    pv[0] = bf_lo(p.x); pv[1] = bf_hi(p.x);
    pv[2] = bf_lo(p.y); pv[3] = bf_hi(p.y);
    pv[4] = bf_lo(p.z); pv[5] = bf_hi(p.z);
    pv[6] = bf_lo(p.w); pv[7] = bf_hi(p.w);
  }
  unsigned short o16[8];
#pragma unroll
  for (int q = 0; q < 8; ++q) {
    float acc = (a0[q] + a1[q]) + (a2[q] + a3[q]);   // fixed tree, deterministic
    o16[q] = f2bf(scale2 * acc - pv[q]);
  }
  uint4 o;
  o.x = (unsigned int)o16[0] | ((unsigned int)o16[1] << 16);
  o.y = (unsigned int)o16[2] | ((unsigned int)o16[3] << 16);
  o.z = (unsigned int)o16[4] | ((unsigned int)o16[5] << 16);
  o.w = (unsigned int)o16[6] | ((unsigned int)o16[7] << 16);
  *(uint4*)&tout[(size_t)j * 512 + coff] = o;
}

// ---------------- GEMM: C[o][n] = sum_kc A[n][kc] * B[kc][o] + bias[o] ----------------
// A = TxAll bf16: 5 blocks of [10000][512] (+pad). B^T = thetabT bf16 [512][2560].
__global__ __launch_bounds__(256) void gemm_kernel(
    const unsigned short* __restrict__ A,
    const unsigned short* __restrict__ Bt,
    const float* __restrict__ bias,
    float* __restrict__ C)
{
  __shared__ __align__(16) char smem[64 * 132 * 4];   // 33792B: tiles(32KB) / epilogue(33KB)
  unsigned short* As = (unsigned short*)smem;         // [128][64] bf16
  unsigned short* Bs = As + 128 * 64;                 // [128 o][64 k] bf16
  float* eps = (float*)smem;                          // [64 o][132] f32

  const int tid = threadIdx.x;
  const int wave = tid >> 6, lane = tid & 63;
  const int l15 = lane & 15, hi = lane >> 4;
  const int wr = wave >> 1, wc = wave & 1;
  const int n0 = blockIdx.x * 128;
  const int o0 = blockIdx.y * 128;

  f32x4 acc[4][4];
#pragma unroll
  for (int a = 0; a < 4; ++a)
#pragma unroll
    for (int b = 0; b < 4; ++b) acc[a][b] = (f32x4){0.f, 0.f, 0.f, 0.f};

  for (int kt = 0; kt < 40; ++kt) {
    const int k0 = kt * 64;
    const int ko = k0 >> 9;
    const int c0 = k0 & 511;
    const unsigned short* Ab = A + (size_t)ko * ((size_t)N_NODES * 512);
#pragma unroll
    for (int q = 0; q < 4; ++q) {
      int idx = (wave * 4 + q) * 64 + lane;     // 16B unit id, 0..1023
      int r = idx >> 3, u = idx & 7;
      gll16(Ab + (size_t)(n0 + r) * 512 + c0 + u * 8, As + (size_t)(wave * 4 + q) * 512);
    }
#pragma unroll
    for (int q = 0; q < 4; ++q) {
      int idx = (wave * 4 + q) * 64 + lane;
      int r = idx >> 3, u = idx & 7;
      gll16(Bt + (size_t)(o0 + r) * 2560 + k0 + u * 8, Bs + (size_t)(wave * 4 + q) * 512);
    }
    __syncthreads();
#pragma unroll
    for (int kk = 0; kk < 2; ++kk) {
      bf16x8 af[4], bfr[4];
#pragma unroll
      for (int mi = 0; mi < 4; ++mi)
        af[mi] = *(const bf16x8*)(As + ((wr * 64 + mi * 16 + l15) * 64 + kk * 32 + hi * 8));
#pragma unroll
      for (int ni = 0; ni < 4; ++ni)
        bfr[ni] = *(const bf16x8*)(Bs + ((wc * 64 + ni * 16 + l15) * 64 + kk * 32 + hi * 8));
#pragma unroll
      for (int mi = 0; mi < 4; ++mi)
#pragma unroll
        for (int ni = 0; ni < 4; ++ni)
          acc[mi][ni] = __builtin_amdgcn_mfma_f32_16x16x32_bf16(af[mi], bfr[ni], acc[mi][ni], 0, 0, 0);
    }
    __syncthreads();
  }

  // epilogue: LDS-transposed coalesced store of C[o][n] + bias
#pragma unroll
  for (int h = 0; h < 2; ++h) {
    __syncthreads();
    if (wc == h) {
#pragma unroll
      for (int mi = 0; mi < 4; ++mi)
#pragma unroll
        for (int ni = 0; ni < 4; ++ni) {
          int o_l = ni * 16 + l15;                   // 0..63 within half
          int nb = wr * 64 + mi * 16 + hi * 4;       // 0..124, x4 aligned
          *(f32x4*)&eps[o_l * 132 + nb] = acc[mi][ni];
        }
    }
    __syncthreads();
#pragma unroll
    for (int q = 0; q < 8; ++q) {
      int unit = q * 256 + tid;                      // 2048 float4 units
      int o_l = unit >> 5, nu = unit & 31;
      int n = n0 + nu * 4;
      if (n < N_NODES) {
        int o = o0 + h * 64 + o_l;
        f32x4 v = *(const f32x4*)&eps[o_l * 132 + nu * 4];
        float bo = bias[o];
        v = v + bo;
        *(f32x4*)&C[(size_t)o * N_NODES + n] = v;
      }
    }
  }
}

extern "C" void kernel_launch(void* const* d_in, const int* in_sizes, int n_in,
                              void* d_out, int out_size, void* d_ws, size_t ws_size,
                              hipStream_t stream)
{
  const float* x        = (const float*)d_in[0];   // [512][10000]
  const float* position = (const float*)d_in[1];   // [10000][3]
  const float* theta    = (const float*)d_in[2];   // [5][512][512]
  const float* bias     = (const float*)d_in[3];   // [512]

  char* ws = (char*)d_ws;
  size_t off = 0;
  auto alloc = [&](size_t bytes) -> void* {
    void* p = ws + off;
    off = (off + bytes + 255) & ~(size_t)255;
    return p;
  };
  unsigned short* TxAll   = (unsigned short*)alloc(5ull * N_NODES * 512 * 2 + 131072); // +128-row pad
  unsigned short* thetabT = (unsigned short*)alloc(512ull * 2560 * 2);
  float4* pos4 = (float4*)alloc((size_t)POS4_PAD * 16);
  int* knn    = (int*)alloc((size_t)NEDGE * 4);
  int* rptr   = (int*)alloc((size_t)(N_NODES + 1) * 4);
  int* counts = (int*)alloc((size_t)N_NODES * 4);
  int* cursor = (int*)alloc((size_t)N_NODES * 4);
  int* rsrc   = (int*)alloc((size_t)NEDGE * 4);
  if (ws_size < off) return;   // insufficient scratch

  // theta [5][512][512] -> thetabT [o=512][kc=2560]
  transpose_f32_bf16<<<dim3(8, 8, 5), 256, 0, stream>>>(
      theta, thetabT, 512, 512, 2560, (size_t)512 * 512, 512);
  // x [512][10000] -> Tx0 [10000][512]
  transpose_f32_bf16<<<dim3(157, 8, 1), 256, 0, stream>>>(
      x, TxAll, 512, N_NODES, 512, 0, 0);

  pos4_kernel<<<40, 256, 0, stream>>>(position, pos4, counts, cursor);
  knn_kernel<<<2500, 256, 0, stream>>>(pos4, knn);

  count_kernel<<<(NEDGE + 255) / 256, 256, 0, stream>>>(knn, counts);
  scan_kernel<<<1, 256, 0, stream>>>(counts, rptr);
  fill_kernel<<<(NEDGE + 255) / 256, 256, 0, stream>>>(knn, rptr, cursor, rsrc);
  sort_kernel<<<(N_NODES + 255) / 256, 256, 0, stream>>>(rptr, rsrc);

  unsigned short* Tx0 = TxAll;
  unsigned short* Tx1 = TxAll + 1ull * N_NODES * 512;
  unsigned short* Tx2 = TxAll + 2ull * N_NODES * 512;
  unsigned short* Tx3 = TxAll + 3ull * N_NODES * 512;
  unsigned short* Tx4 = TxAll + 4ull * N_NODES * 512;

  // Tx1 = prop(Tx0) = -0.05*sum ; Tx_k = 2*prop(Tx_{k-1}) - Tx_{k-2} = -0.10*sum - prev
  prop_kernel<<<2500, 256, 0, stream>>>(Tx0, nullptr, Tx1, rptr, rsrc, -0.05f);
  prop_kernel<<<2500, 256, 0, stream>>>(Tx1, Tx0,     Tx2, rptr, rsrc, -0.10f);
  prop_kernel<<<2500, 256, 0, stream>>>(Tx2, Tx1,     Tx3, rptr, rsrc, -0.10f);
  prop_kernel<<<2500, 256, 0, stream>>>(Tx3, Tx2,     Tx4, rptr, rsrc, -0.10f);

  gemm_kernel<<<dim3(79, 4), 256, 0, stream>>>(TxAll, thetabT, bias, (float*)d_out);
}

// Round 9
// 311.793 us; speedup vs baseline: 1.4058x; 1.2533x over previous
//
// Round 9: bitonic wave sort_kernel; int4 scan (+cell scan block); spatial
// counting-sort perm + XCD-chunked prop scheduling for L2-local gathers.
// knn (133us known-good), gemm, count, fill unchanged from round 8.
#include <hip/hip_runtime.h>
#include <hip/hip_bf16.h>
#include <cstdint>
#include <cstddef>

#define N_NODES 10000
#define KNN_K 20
#define NEDGE (N_NODES * KNN_K)
#define NBATCH 157                 // ceil(10000/64)
#define POS4_PAD 10048             // 157*64
#define NCELL 512                  // 8x8x8 spatial cells
#define NPX 1250                   // nodes per XCD chunk (10000/8)

using bf16x8 = __attribute__((ext_vector_type(8))) short;
using f32x4  = __attribute__((ext_vector_type(4))) float;

__device__ __forceinline__ float bf_lo(unsigned int u) {
  union { unsigned int i; float f; } c; c.i = u << 16; return c.f;
}
__device__ __forceinline__ float bf_hi(unsigned int u) {
  union { unsigned int i; float f; } c; c.i = u & 0xFFFF0000u; return c.f;
}
__device__ __forceinline__ unsigned short f2bf(float f) {
  union { float f; unsigned int i; } c; c.f = f;
  unsigned int u = c.i;
  u += 0x7FFFu + ((u >> 16) & 1u);   // RNE
  return (unsigned short)(u >> 16);
}

__device__ __forceinline__ void gll16(const void* g, void* l) {
  __builtin_amdgcn_global_load_lds(
      (const __attribute__((address_space(1))) unsigned int*)g,
      (__attribute__((address_space(3))) unsigned int*)l,
      16, 0, 0);
}

// ---------------- transpose f32 [srows][scols] -> bf16 dst[col][dcol0 + row] ----------------
__global__ __launch_bounds__(256) void transpose_f32_bf16(
    const float* __restrict__ src0, unsigned short* __restrict__ dst,
    int srows, int scols, int dstride, size_t slice_elems, int dcol_per_slice)
{
  __shared__ float lds[64 * 65];
  const int z = blockIdx.z;
  const float* src = src0 + (size_t)z * slice_elems;
  const int dcol0 = z * dcol_per_slice;
  const int c0 = blockIdx.x * 64;
  const int r0 = blockIdx.y * 64;
  const int tid = threadIdx.x;
#pragma unroll
  for (int q = 0; q < 4; ++q) {
    int unit = q * 256 + tid;            // 1024 float4 units
    int rr = unit >> 4;                  // 0..63
    int cu = unit & 15;                  // 0..15
    int r = r0 + rr, c = c0 + cu * 4;
    float4 v = make_float4(0.f, 0.f, 0.f, 0.f);
    if (r < srows && c + 3 < scols) v = *(const float4*)&src[(size_t)r * scols + c];
    lds[rr * 65 + cu * 4 + 0] = v.x;
    lds[rr * 65 + cu * 4 + 1] = v.y;
    lds[rr * 65 + cu * 4 + 2] = v.z;
    lds[rr * 65 + cu * 4 + 3] = v.w;
  }
  __syncthreads();
#pragma unroll
  for (int q = 0; q < 2; ++q) {
    int unit = q * 256 + tid;            // 512 units of 8 bf16
    int cl = unit >> 3;                  // src col within tile (= dst row)
    int ru = unit & 7;
    int c = c0 + cl;
    if (c < scols) {
      unsigned short tmp[8];
#pragma unroll
      for (int j = 0; j < 8; ++j) tmp[j] = f2bf(lds[(ru * 8 + j) * 65 + cl]);
      uint4 o;
      o.x = (unsigned int)tmp[0] | ((unsigned int)tmp[1] << 16);
      o.y = (unsigned int)tmp[2] | ((unsigned int)tmp[3] << 16);
      o.z = (unsigned int)tmp[4] | ((unsigned int)tmp[5] << 16);
      o.w = (unsigned int)tmp[6] | ((unsigned int)tmp[7] << 16);
      *(uint4*)&dst[(size_t)c * dstride + dcol0 + r0 + ru * 8] = o;
    }
  }
}

// ---- pos4: pack (x,y,z,|p|^2); pad w=+INF; zero counts/cursor; spatial cell hist ----
__global__ __launch_bounds__(256) void pos4_kernel(
    const float* __restrict__ pos, float4* __restrict__ pos4,
    int* __restrict__ counts, int* __restrict__ cursor,
    int* __restrict__ cellid, int* __restrict__ cellcnt)
{
  int c = blockIdx.x * 256 + threadIdx.x;      // grid 40 -> 10240 threads
  if (c < POS4_PAD) {
    float4 v;
    if (c < N_NODES) {
      float x = pos[c * 3 + 0], y = pos[c * 3 + 1], z = pos[c * 3 + 2];
      v = make_float4(x, y, z, x * x + y * y + z * z);
      int cx = min(7, max(0, (int)floorf(x + 4.0f)));
      int cy = min(7, max(0, (int)floorf(y + 4.0f)));
      int cz = min(7, max(0, (int)floorf(z + 4.0f)));
      int cell = (cx << 6) | (cy << 3) | cz;
      cellid[c] = cell;
      atomicAdd(&cellcnt[cell], 1);
      counts[c] = 0; cursor[c] = 0;
    } else {
      v = make_float4(0.f, 0.f, 0.f, __builtin_inff());   // d -> +INF
    }
    pos4[c] = v;
  }
}

// identical expression in both phases -> bit-identical distances
__device__ __forceinline__ float knn_dist(float4 pi, float4 s) {
  float dot = fmaf(pi.x, s.x, fmaf(pi.y, s.y, pi.z * s.z));
  return fmaf(-2.0f, dot, pi.w + s.w);
}

// ---------------- kNN (round-6 exact): wave/node; f32 top-8 via med3; tau; recovery ----------------
__global__ __launch_bounds__(256) void knn_kernel(
    const float4* __restrict__ pos4, int* __restrict__ knn_out)
{
  const int lane = threadIdx.x & 63, wave = threadIdx.x >> 6;
  const int i = blockIdx.x * 4 + wave;
  const float4 pi = pos4[i];
  const float INF = __builtin_inff();

  float r0 = INF, r1 = INF, r2 = INF, r3 = INF;
  float r4 = INF, r5 = INF, r6 = INF, r7 = INF;

  // phase 1: per-lane top-8 of distances (branchless med3 insert network)
#pragma unroll 4
  for (int b = 0; b < NBATCH; ++b) {
    const int cid = b * 64 + lane;
    const float4 s = pos4[cid];
    float d = knn_dist(pi, s);                    // pad rows: +INF
    float k = (cid == i) ? INF : d;               // exclude self
    asm("v_med3_f32 %0, %1, %2, %3" : "=v"(r7) : "v"(k), "v"(r6), "v"(r7));
    asm("v_med3_f32 %0, %1, %2, %3" : "=v"(r6) : "v"(k), "v"(r5), "v"(r6));
    asm("v_med3_f32 %0, %1, %2, %3" : "=v"(r5) : "v"(k), "v"(r4), "v"(r5));
    asm("v_med3_f32 %0, %1, %2, %3" : "=v"(r4) : "v"(k), "v"(r3), "v"(r4));
    asm("v_med3_f32 %0, %1, %2, %3" : "=v"(r3) : "v"(k), "v"(r2), "v"(r3));
    asm("v_med3_f32 %0, %1, %2, %3" : "=v"(r2) : "v"(k), "v"(r1), "v"(r2));
    asm("v_med3_f32 %0, %1, %2, %3" : "=v"(r1) : "v"(k), "v"(r0), "v"(r1));
    r0 = fminf(r0, k);
  }

  // merge: 20 duplicate-safe extract-min rounds -> tau = exact 20th smallest
  float tau = INF;
#pragma unroll
  for (int r = 0; r < KNN_K; ++r) {
    float m = r0;
    m = fminf(m, __shfl_xor(m, 1));
    m = fminf(m, __shfl_xor(m, 2));
    m = fminf(m, __shfl_xor(m, 4));
    m = fminf(m, __shfl_xor(m, 8));
    m = fminf(m, __shfl_xor(m, 16));
    m = fminf(m, __shfl_xor(m, 32));
    unsigned long long who = __ballot(r0 == m);
    int srcl = __ffsll(who) - 1;                  // pop exactly one holder
    if (lane == srcl) {
      r0 = r1; r1 = r2; r2 = r3; r3 = r4; r4 = r5; r5 = r6; r6 = r7; r7 = INF;
    }
    tau = m;                                       // after loop: 20th smallest
  }

  // phase 2: recover indices — all {d < tau}, then {d == tau} lowest-index first
  int cnt = 0;
  for (int b = 0; b < NBATCH; ++b) {
    const int cid = b * 64 + lane;
    const float4 s = pos4[cid];
    float d = knn_dist(pi, s);
    bool valid = (cid != i);                      // pad rows: d=INF, self-excluded
    unsigned long long less = __ballot(valid && d < tau);
    unsigned long long eq   = __ballot(valid && d == tau);
    if (less) {
      if (valid && d < tau) {
        int pos = cnt + (int)__popcll(less & ((1ull << lane) - 1ull));
        if (pos < KNN_K) knn_out[i * KNN_K + pos] = cid;
      }
      cnt += (int)__popcll(less);
    }
    if (eq && cnt < KNN_K) {
      if (valid && d == tau) {
        int pos = cnt + (int)__popcll(eq & ((1ull << lane) - 1ull));
        if (pos < KNN_K) knn_out[i * KNN_K + pos] = cid;
      }
      cnt = min(KNN_K, cnt + (int)__popcll(eq));
    }
  }
}

// ---------------- reverse-CSR build ----------------
__global__ __launch_bounds__(256) void count_kernel(
    const int* __restrict__ knn, int* __restrict__ counts)
{
  int e = blockIdx.x * 256 + threadIdx.x;
  if (e < NEDGE) atomicAdd(&counts[knn[e]], 1);
}

// block 0: node-degree exclusive scan (int4 loads; 250 threads x 40 exact)
// block 1: cell-histogram exclusive scan (512 cells, 2/thread)
__global__ __launch_bounds__(256) void scan_kernel(
    const int* __restrict__ counts, int* __restrict__ rptr,
    const int* __restrict__ cellcnt, int* __restrict__ cellptr)
{
  __shared__ int part[256];
  const int tid = threadIdx.x;
  if (blockIdx.x == 1) {
    int c0 = cellcnt[tid * 2], c1 = cellcnt[tid * 2 + 1];
    int s = c0 + c1;
    part[tid] = s;
    __syncthreads();
    for (int off = 1; off < 256; off <<= 1) {
      int add = (tid >= off) ? part[tid - off] : 0;
      __syncthreads();
      part[tid] += add;
      __syncthreads();
    }
    int off0 = part[tid] - s;
    cellptr[tid * 2] = off0;
    cellptr[tid * 2 + 1] = off0 + c0;
    return;
  }
  const int base = tid * 40;                       // 250*40 = 10000 exact
  int s = 0;
  int cv[40];
  if (tid < 250) {
#pragma unroll
    for (int q = 0; q < 10; ++q) {
      int4 v = *(const int4*)&counts[base + q * 4];
      cv[q * 4 + 0] = v.x; cv[q * 4 + 1] = v.y;
      cv[q * 4 + 2] = v.z; cv[q * 4 + 3] = v.w;
      s += v.x + v.y + v.z + v.w;
    }
  }
  part[tid] = s;
  __syncthreads();
  for (int off = 1; off < 256; off <<= 1) {
    int add = (tid >= off) ? part[tid - off] : 0;
    __syncthreads();
    part[tid] += add;
    __syncthreads();
  }
  int run = part[tid] - s;                         // exclusive offset
  if (tid < 250) {
#pragma unroll
    for (int q = 0; q < 40; ++q) { rptr[base + q] = run; run += cv[q]; }
  }
  if (tid == 255) rptr[N_NODES] = run;
}

__global__ __launch_bounds__(256) void fill_kernel(
    const int* __restrict__ knn, const int* __restrict__ rptr,
    int* __restrict__ cursor, int* __restrict__ rsrc)
{
  int e = blockIdx.x * 256 + threadIdx.x;
  if (e < NEDGE) {
    int j = knn[e];
    int i = e / KNN_K;
    int p = atomicAdd(&cursor[j], 1);
    rsrc[rptr[j] + p] = i;
  }
}

// counting-sort scatter: perm = nodes grouped by spatial cell (order within
// cell nondeterministic; output-invariant — perm only picks WHICH wave owns j)
__global__ __launch_bounds__(256) void perm_kernel(
    const int* __restrict__ cellid, const int* __restrict__ cellptr,
    int* __restrict__ cellcur, int* __restrict__ perm)
{
  int c = blockIdx.x * 256 + threadIdx.x;
  if (c < N_NODES) {
    int cell = cellid[c];
    int p = atomicAdd(&cellcur[cell], 1);
    perm[cellptr[cell] + p] = c;
  }
}

// sort each reverse-adjacency list ascending -> deterministic gather order.
// wave-per-node bitonic-64 via shfl_xor; serial fallback for deg > 64 (~never).
__global__ __launch_bounds__(256) void sort_kernel(
    const int* __restrict__ rptr, int* __restrict__ rsrc)
{
  const int lane = threadIdx.x & 63, wave = threadIdx.x >> 6;
  const int j = blockIdx.x * 4 + wave;
  const int s0 = rptr[j], s1 = rptr[j + 1], deg = s1 - s0;
  if (deg <= 64) {
    int v = (lane < deg) ? rsrc[s0 + lane] : 0x7FFFFFFF;
#pragma unroll
    for (int k = 2; k <= 64; k <<= 1) {
#pragma unroll
      for (int m = k >> 1; m > 0; m >>= 1) {
        int other = __shfl_xor(v, m);
        bool up = ((lane & k) == 0);
        bool lower = ((lane & m) == 0);
        v = (up == lower) ? min(v, other) : max(v, other);
      }
    }
    if (lane < deg) rsrc[s0 + lane] = v;
  } else if (lane == 0) {
    for (int a = s0 + 1; a < s1; ++a) {
      int v = rsrc[a];
      int b = a - 1;
      while (b >= s0 && rsrc[b] > v) { rsrc[b + 1] = rsrc[b]; --b; }
      rsrc[b + 1] = v;
    }
  }
}

// ---------------- prop: out[j] = scale2 * sum_{i in rev(j)} t[i] - prev[j] ----------------
// XCD-chunked spatial schedule: blockIdx&7 = XCD (HW round-robin) processes one
// contiguous perm chunk -> gather working set ~1.3MB fits the XCD's 4MB L2.
__global__ __launch_bounds__(256) void prop_kernel(
    const unsigned short* __restrict__ tin, const unsigned short* __restrict__ tprev,
    unsigned short* __restrict__ tout, const int* __restrict__ rptr,
    const int* __restrict__ rsrc, const int* __restrict__ perm, float scale2)
{
  const int wave = threadIdx.x >> 6, lane = threadIdx.x & 63;
  const int b = blockIdx.x;                        // grid 2504
  const int xcd = b & 7, qb = b >> 3;
  const int local = qb * 4 + wave;
  if (local >= NPX) return;                        // no barriers below: safe
  const int j = perm[xcd * NPX + local];
  const int s0 = rptr[j], s1 = rptr[j + 1];
  const size_t coff = (size_t)lane * 8;

  float a0[8], a1[8], a2[8], a3[8];
#pragma unroll
  for (int q = 0; q < 8; ++q) { a0[q] = 0.f; a1[q] = 0.f; a2[q] = 0.f; a3[q] = 0.f; }

  for (int base = s0; base < s1; base += 64) {
    const int clen = min(64, s1 - base);
    int myidx = (base + lane < s1) ? rsrc[base + lane] : 0;
    int t = 0;
    for (; t + 4 <= clen; t += 4) {
      int i0 = __shfl(myidx, t);
      int i1 = __shfl(myidx, t + 1);
      int i2 = __shfl(myidx, t + 2);
      int i3 = __shfl(myidx, t + 3);
      uint4 v0 = *(const uint4*)&tin[(size_t)i0 * 512 + coff];
      uint4 v1 = *(const uint4*)&tin[(size_t)i1 * 512 + coff];
      uint4 v2 = *(const uint4*)&tin[(size_t)i2 * 512 + coff];
      uint4 v3 = *(const uint4*)&tin[(size_t)i3 * 512 + coff];
      a0[0] += bf_lo(v0.x); a0[1] += bf_hi(v0.x); a0[2] += bf_lo(v0.y); a0[3] += bf_hi(v0.y);
      a0[4] += bf_lo(v0.z); a0[5] += bf_hi(v0.z); a0[6] += bf_lo(v0.w); a0[7] += bf_hi(v0.w);
      a1[0] += bf_lo(v1.x); a1[1] += bf_hi(v1.x); a1[2] += bf_lo(v1.y); a1[3] += bf_hi(v1.y);
      a1[4] += bf_lo(v1.z); a1[5] += bf_hi(v1.z); a1[6] += bf_lo(v1.w); a1[7] += bf_hi(v1.w);
      a2[0] += bf_lo(v2.x); a2[1] += bf_hi(v2.x); a2[2] += bf_lo(v2.y); a2[3] += bf_hi(v2.y);
      a2[4] += bf_lo(v2.z); a2[5] += bf_hi(v2.z); a2[6] += bf_lo(v2.w); a2[7] += bf_hi(v2.w);
      a3[0] += bf_lo(v3.x); a3[1] += bf_hi(v3.x); a3[2] += bf_lo(v3.y); a3[3] += bf_hi(v3.y);
      a3[4] += bf_lo(v3.z); a3[5] += bf_hi(v3.z); a3[6] += bf_lo(v3.w); a3[7] += bf_hi(v3.w);
    }
    for (; t < clen; ++t) {
      int i0 = __shfl(myidx, t);
      uint4 v0 = *(const uint4*)&tin[(size_t)i0 * 512 + coff];
      a0[0] += bf_lo(v0.x); a0[1] += bf_hi(v0.x); a0[2] += bf_lo(v0.y); a0[3] += bf_hi(v0.y);
      a0[4] += bf_lo(v0.z); a0[5] += bf_hi(v0.z); a0[6] += bf_lo(v0.w); a0[7] += bf_hi(v0.w);
    }
  }

  float pv[8] = {0.f, 0.f, 0.f, 0.f, 0.f, 0.f, 0.f, 0.f};
  if (tprev != nullptr) {
    uint4 p = *(const uint4*)&tprev[(size_t)j * 512 + coff];
    pv[0] = bf_lo(p.x); pv[1] = bf_hi(p.x);
    pv[2] = bf_lo(p.y); pv[3] = bf_hi(p.y);
    pv[4] = bf_lo(p.z); pv[5] = bf_hi(p.z);
    pv[6] = bf_lo(p.w); pv[7] = bf_hi(p.w);
  }
  unsigned short o16[8];
#pragma unroll
  for (int q = 0; q < 8; ++q) {
    float acc = (a0[q] + a1[q]) + (a2[q] + a3[q]);   // fixed tree, deterministic
    o16[q] = f2bf(scale2 * acc - pv[q]);
  }
  uint4 o;
  o.x = (unsigned int)o16[0] | ((unsigned int)o16[1] << 16);
  o.y = (unsigned int)o16[2] | ((unsigned int)o16[3] << 16);
  o.z = (unsigned int)o16[4] | ((unsigned int)o16[5] << 16);
  o.w = (unsigned int)o16[6] | ((unsigned int)o16[7] << 16);
  *(uint4*)&tout[(size_t)j * 512 + coff] = o;
}

// ---------------- GEMM: C[o][n] = sum_kc A[n][kc] * B[kc][o] + bias[o] ----------------
// A = TxAll bf16: 5 blocks of [10000][512] (+pad). B^T = thetabT bf16 [512][2560].
__global__ __launch_bounds__(256) void gemm_kernel(
    const unsigned short* __restrict__ A,
    const unsigned short* __restrict__ Bt,
    const float* __restrict__ bias,
    float* __restrict__ C)
{
  __shared__ __align__(16) char smem[64 * 132 * 4];   // 33792B: tiles(32KB) / epilogue(33KB)
  unsigned short* As = (unsigned short*)smem;         // [128][64] bf16
  unsigned short* Bs = As + 128 * 64;                 // [128 o][64 k] bf16
  float* eps = (float*)smem;                          // [64 o][132] f32

  const int tid = threadIdx.x;
  const int wave = tid >> 6, lane = tid & 63;
  const int l15 = lane & 15, hi = lane >> 4;
  const int wr = wave >> 1, wc = wave & 1;
  const int n0 = blockIdx.x * 128;
  const int o0 = blockIdx.y * 128;

  f32x4 acc[4][4];
#pragma unroll
  for (int a = 0; a < 4; ++a)
#pragma unroll
    for (int b = 0; b < 4; ++b) acc[a][b] = (f32x4){0.f, 0.f, 0.f, 0.f};

  for (int kt = 0; kt < 40; ++kt) {
    const int k0 = kt * 64;
    const int ko = k0 >> 9;
    const int c0 = k0 & 511;
    const unsigned short* Ab = A + (size_t)ko * ((size_t)N_NODES * 512);
#pragma unroll
    for (int q = 0; q < 4; ++q) {
      int idx = (wave * 4 + q) * 64 + lane;     // 16B unit id, 0..1023
      int r = idx >> 3, u = idx & 7;
      gll16(Ab + (size_t)(n0 + r) * 512 + c0 + u * 8, As + (size_t)(wave * 4 + q) * 512);
    }
#pragma unroll
    for (int q = 0; q < 4; ++q) {
      int idx = (wave * 4 + q) * 64 + lane;
      int r = idx >> 3, u = idx & 7;
      gll16(Bt + (size_t)(o0 + r) * 2560 + k0 + u * 8, Bs + (size_t)(wave * 4 + q) * 512);
    }
    __syncthreads();
#pragma unroll
    for (int kk = 0; kk < 2; ++kk) {
      bf16x8 af[4], bfr[4];
#pragma unroll
      for (int mi = 0; mi < 4; ++mi)
        af[mi] = *(const bf16x8*)(As + ((wr * 64 + mi * 16 + l15) * 64 + kk * 32 + hi * 8));
#pragma unroll
      for (int ni = 0; ni < 4; ++ni)
        bfr[ni] = *(const bf16x8*)(Bs + ((wc * 64 + ni * 16 + l15) * 64 + kk * 32 + hi * 8));
#pragma unroll
      for (int mi = 0; mi < 4; ++mi)
#pragma unroll
        for (int ni = 0; ni < 4; ++ni)
          acc[mi][ni] = __builtin_amdgcn_mfma_f32_16x16x32_bf16(af[mi], bfr[ni], acc[mi][ni], 0, 0, 0);
    }
    __syncthreads();
  }

  // epilogue: LDS-transposed coalesced store of C[o][n] + bias
#pragma unroll
  for (int h = 0; h < 2; ++h) {
    __syncthreads();
    if (wc == h) {
#pragma unroll
      for (int mi = 0; mi < 4; ++mi)
#pragma unroll
        for (int ni = 0; ni < 4; ++ni) {
          int o_l = ni * 16 + l15;                   // 0..63 within half
          int nb = wr * 64 + mi * 16 + hi * 4;       // 0..124, x4 aligned
          *(f32x4*)&eps[o_l * 132 + nb] = acc[mi][ni];
        }
    }
    __syncthreads();
#pragma unroll
    for (int q = 0; q < 8; ++q) {
      int unit = q * 256 + tid;                      // 2048 float4 units
      int o_l = unit >> 5, nu = unit & 31;
      int n = n0 + nu * 4;
      if (n < N_NODES) {
        int o = o0 + h * 64 + o_l;
        f32x4 v = *(const f32x4*)&eps[o_l * 132 + nu * 4];
        float bo = bias[o];
        v = v + bo;
        *(f32x4*)&C[(size_t)o * N_NODES + n] = v;
      }
    }
  }
}

extern "C" void kernel_launch(void* const* d_in, const int* in_sizes, int n_in,
                              void* d_out, int out_size, void* d_ws, size_t ws_size,
                              hipStream_t stream)
{
  const float* x        = (const float*)d_in[0];   // [512][10000]
  const float* position = (const float*)d_in[1];   // [10000][3]
  const float* theta    = (const float*)d_in[2];   // [5][512][512]
  const float* bias     = (const float*)d_in[3];   // [512]

  char* ws = (char*)d_ws;
  size_t off = 0;
  auto alloc = [&](size_t bytes) -> void* {
    void* p = ws + off;
    off = (off + bytes + 255) & ~(size_t)255;
    return p;
  };
  unsigned short* TxAll   = (unsigned short*)alloc(5ull * N_NODES * 512 * 2 + 131072); // +128-row pad
  unsigned short* thetabT = (unsigned short*)alloc(512ull * 2560 * 2);
  float4* pos4 = (float4*)alloc((size_t)POS4_PAD * 16);
  int* knn    = (int*)alloc((size_t)NEDGE * 4);
  int* rptr   = (int*)alloc((size_t)(N_NODES + 1) * 4);
  int* counts = (int*)alloc((size_t)N_NODES * 4);
  int* cursor = (int*)alloc((size_t)N_NODES * 4);
  int* rsrc   = (int*)alloc((size_t)NEDGE * 4);
  int* cellcnt = (int*)alloc((size_t)NCELL * 4);   // contiguous with cellcur:
  int* cellcur = (int*)alloc((size_t)NCELL * 4);   // one 4KB memset covers both
  int* cellptr = (int*)alloc((size_t)NCELL * 4);
  int* cellid  = (int*)alloc((size_t)N_NODES * 4);
  int* perm    = (int*)alloc((size_t)N_NODES * 4);
  if (ws_size < off) return;   // insufficient scratch

  // theta [5][512][512] -> thetabT [o=512][kc=2560]
  transpose_f32_bf16<<<dim3(8, 8, 5), 256, 0, stream>>>(
      theta, thetabT, 512, 512, 2560, (size_t)512 * 512, 512);
  // x [512][10000] -> Tx0 [10000][512]
  transpose_f32_bf16<<<dim3(157, 8, 1), 256, 0, stream>>>(
      x, TxAll, 512, N_NODES, 512, 0, 0);

  hipMemsetAsync(cellcnt, 0, ((char*)cellptr - (char*)cellcnt), stream);
  pos4_kernel<<<40, 256, 0, stream>>>(position, pos4, counts, cursor, cellid, cellcnt);
  knn_kernel<<<2500, 256, 0, stream>>>(pos4, knn);

  count_kernel<<<(NEDGE + 255) / 256, 256, 0, stream>>>(knn, counts);
  scan_kernel<<<2, 256, 0, stream>>>(counts, rptr, cellcnt, cellptr);
  fill_kernel<<<(NEDGE + 255) / 256, 256, 0, stream>>>(knn, rptr, cursor, rsrc);
  perm_kernel<<<40, 256, 0, stream>>>(cellid, cellptr, cellcur, perm);
  sort_kernel<<<2500, 256, 0, stream>>>(rptr, rsrc);

  unsigned short* Tx0 = TxAll;
  unsigned short* Tx1 = TxAll + 1ull * N_NODES * 512;
  unsigned short* Tx2 = TxAll + 2ull * N_NODES * 512;
  unsigned short* Tx3 = TxAll + 3ull * N_NODES * 512;
  unsigned short* Tx4 = TxAll + 4ull * N_NODES * 512;

  // Tx1 = prop(Tx0) = -0.05*sum ; Tx_k = 2*prop(Tx_{k-1}) - Tx_{k-2} = -0.10*sum - prev
  prop_kernel<<<2504, 256, 0, stream>>>(Tx0, nullptr, Tx1, rptr, rsrc, perm, -0.05f);
  prop_kernel<<<2504, 256, 0, stream>>>(Tx1, Tx0,     Tx2, rptr, rsrc, perm, -0.10f);
  prop_kernel<<<2504, 256, 0, stream>>>(Tx2, Tx1,     Tx3, rptr, rsrc, perm, -0.10f);
  prop_kernel<<<2504, 256, 0, stream>>>(Tx3, Tx2,     Tx4, rptr, rsrc, perm, -0.10f);

  gemm_kernel<<<dim3(79, 4), 256, 0, stream>>>(TxAll, thetabT, bias, (float*)d_out);
}

// Round 10
// 265.169 us; speedup vs baseline: 1.6530x; 1.1758x over previous
//
// Round 10: grid-pruned exact kNN (16^3 cells, h=0.5) — scan <=27-cell block,
// accept iff tau < margin^2 (provably exact), else round-6 full-scan fallback.
// Cell infra upgraded to 4096 cells; pos4s = cell-sorted candidates.
// sort/count/fill/props/gemm unchanged from round 9 (311.8us, knn 133.6us).
#include <hip/hip_runtime.h>
#include <hip/hip_bf16.h>
#include <cstdint>
#include <cstddef>

#define N_NODES 10000
#define KNN_K 20
#define NEDGE (N_NODES * KNN_K)
#define NBATCH 157                 // ceil(10000/64)
#define POS4_PAD 10048             // 157*64
#define NCELL 4096                 // 16x16x16 spatial cells, h=0.5
#define NPX 1250                   // nodes per XCD chunk (10000/8)

using bf16x8 = __attribute__((ext_vector_type(8))) short;
using f32x4  = __attribute__((ext_vector_type(4))) float;

__device__ __forceinline__ float bf_lo(unsigned int u) {
  union { unsigned int i; float f; } c; c.i = u << 16; return c.f;
}
__device__ __forceinline__ float bf_hi(unsigned int u) {
  union { unsigned int i; float f; } c; c.i = u & 0xFFFF0000u; return c.f;
}
__device__ __forceinline__ unsigned short f2bf(float f) {
  union { float f; unsigned int i; } c; c.f = f;
  unsigned int u = c.i;
  u += 0x7FFFu + ((u >> 16) & 1u);   // RNE
  return (unsigned short)(u >> 16);
}

__device__ __forceinline__ void gll16(const void* g, void* l) {
  __builtin_amdgcn_global_load_lds(
      (const __attribute__((address_space(1))) unsigned int*)g,
      (__attribute__((address_space(3))) unsigned int*)l,
      16, 0, 0);
}

// ---------------- transpose f32 [srows][scols] -> bf16 dst[col][dcol0 + row] ----------------
__global__ __launch_bounds__(256) void transpose_f32_bf16(
    const float* __restrict__ src0, unsigned short* __restrict__ dst,
    int srows, int scols, int dstride, size_t slice_elems, int dcol_per_slice)
{
  __shared__ float lds[64 * 65];
  const int z = blockIdx.z;
  const float* src = src0 + (size_t)z * slice_elems;
  const int dcol0 = z * dcol_per_slice;
  const int c0 = blockIdx.x * 64;
  const int r0 = blockIdx.y * 64;
  const int tid = threadIdx.x;
#pragma unroll
  for (int q = 0; q < 4; ++q) {
    int unit = q * 256 + tid;            // 1024 float4 units
    int rr = unit >> 4;                  // 0..63
    int cu = unit & 15;                  // 0..15
    int r = r0 + rr, c = c0 + cu * 4;
    float4 v = make_float4(0.f, 0.f, 0.f, 0.f);
    if (r < srows && c + 3 < scols) v = *(const float4*)&src[(size_t)r * scols + c];
    lds[rr * 65 + cu * 4 + 0] = v.x;
    lds[rr * 65 + cu * 4 + 1] = v.y;
    lds[rr * 65 + cu * 4 + 2] = v.z;
    lds[rr * 65 + cu * 4 + 3] = v.w;
  }
  __syncthreads();
#pragma unroll
  for (int q = 0; q < 2; ++q) {
    int unit = q * 256 + tid;            // 512 units of 8 bf16
    int cl = unit >> 3;                  // src col within tile (= dst row)
    int ru = unit & 7;
    int c = c0 + cl;
    if (c < scols) {
      unsigned short tmp[8];
#pragma unroll
      for (int j = 0; j < 8; ++j) tmp[j] = f2bf(lds[(ru * 8 + j) * 65 + cl]);
      uint4 o;
      o.x = (unsigned int)tmp[0] | ((unsigned int)tmp[1] << 16);
      o.y = (unsigned int)tmp[2] | ((unsigned int)tmp[3] << 16);
      o.z = (unsigned int)tmp[4] | ((unsigned int)tmp[5] << 16);
      o.w = (unsigned int)tmp[6] | ((unsigned int)tmp[7] << 16);
      *(uint4*)&dst[(size_t)c * dstride + dcol0 + r0 + ru * 8] = o;
    }
  }
}

// ---- pos4: pack (x,y,z,|p|^2); pad w=+INF; zero counts/cursor; 16^3 cell hist ----
__global__ __launch_bounds__(256) void pos4_kernel(
    const float* __restrict__ pos, float4* __restrict__ pos4,
    int* __restrict__ counts, int* __restrict__ cursor,
    int* __restrict__ cellid, int* __restrict__ cellcnt)
{
  int c = blockIdx.x * 256 + threadIdx.x;      // grid 40 -> 10240 threads
  if (c < POS4_PAD) {
    float4 v;
    if (c < N_NODES) {
      float x = pos[c * 3 + 0], y = pos[c * 3 + 1], z = pos[c * 3 + 2];
      v = make_float4(x, y, z, x * x + y * y + z * z);
      int cx = min(15, max(0, (int)floorf((x + 4.0f) * 2.0f)));
      int cy = min(15, max(0, (int)floorf((y + 4.0f) * 2.0f)));
      int cz = min(15, max(0, (int)floorf((z + 4.0f) * 2.0f)));
      int cell = (cx << 8) | (cy << 4) | cz;
      cellid[c] = cell;
      atomicAdd(&cellcnt[cell], 1);
      counts[c] = 0; cursor[c] = 0;
    } else {
      v = make_float4(0.f, 0.f, 0.f, __builtin_inff());   // d -> +INF
    }
    pos4[c] = v;
  }
}

// cell-histogram exclusive scan: 1 block, 16 cells/thread
__global__ __launch_bounds__(256) void cellscan_kernel(
    const int* __restrict__ cellcnt, int* __restrict__ cellptr)
{
  __shared__ int part[256];
  const int tid = threadIdx.x;
  const int base = tid * 16;
  int cv[16];
  int s = 0;
#pragma unroll
  for (int q = 0; q < 4; ++q) {
    int4 v = *(const int4*)&cellcnt[base + q * 4];
    cv[q * 4 + 0] = v.x; cv[q * 4 + 1] = v.y;
    cv[q * 4 + 2] = v.z; cv[q * 4 + 3] = v.w;
    s += v.x + v.y + v.z + v.w;
  }
  part[tid] = s;
  __syncthreads();
  for (int off = 1; off < 256; off <<= 1) {
    int add = (tid >= off) ? part[tid - off] : 0;
    __syncthreads();
    part[tid] += add;
    __syncthreads();
  }
  int run = part[tid] - s;
#pragma unroll
  for (int q = 0; q < 16; ++q) { cellptr[base + q] = run; run += cv[q]; }
  if (tid == 255) cellptr[NCELL] = run;
}

// counting-sort scatter: perm (cell-grouped node ids) + pos4s (sorted coords)
__global__ __launch_bounds__(256) void perm_kernel(
    const int* __restrict__ cellid, const int* __restrict__ cellptr,
    int* __restrict__ cellcur, int* __restrict__ perm,
    const float4* __restrict__ pos4, float4* __restrict__ pos4s)
{
  int c = blockIdx.x * 256 + threadIdx.x;
  if (c < N_NODES) {
    int cell = cellid[c];
    int p = atomicAdd(&cellcur[cell], 1);
    int slot = cellptr[cell] + p;
    perm[slot] = c;
    pos4s[slot] = pos4[c];
  }
}

// identical expression everywhere -> bit-identical distances
__device__ __forceinline__ float knn_dist(float4 pi, float4 s) {
  float dot = fmaf(pi.x, s.x, fmaf(pi.y, s.y, pi.z * s.z));
  return fmaf(-2.0f, dot, pi.w + s.w);
}

__device__ __forceinline__ void insert8(float r[8], float k) {
  // r ascending; r_j = median(k, r_{j-1}, r_j)
  asm("v_med3_f32 %0, %1, %2, %3" : "=v"(r[7]) : "v"(k), "v"(r[6]), "v"(r[7]));
  asm("v_med3_f32 %0, %1, %2, %3" : "=v"(r[6]) : "v"(k), "v"(r[5]), "v"(r[6]));
  asm("v_med3_f32 %0, %1, %2, %3" : "=v"(r[5]) : "v"(k), "v"(r[4]), "v"(r[5]));
  asm("v_med3_f32 %0, %1, %2, %3" : "=v"(r[4]) : "v"(k), "v"(r[3]), "v"(r[4]));
  asm("v_med3_f32 %0, %1, %2, %3" : "=v"(r[3]) : "v"(k), "v"(r[2]), "v"(r[3]));
  asm("v_med3_f32 %0, %1, %2, %3" : "=v"(r[2]) : "v"(k), "v"(r[1]), "v"(r[2]));
  asm("v_med3_f32 %0, %1, %2, %3" : "=v"(r[1]) : "v"(k), "v"(r[0]), "v"(r[1]));
  r[0] = fminf(r[0], k);
}

__device__ __forceinline__ float merge_tau20(float r[8], int lane) {
  const float INF = __builtin_inff();
  float tau = INF;
#pragma unroll
  for (int t = 0; t < KNN_K; ++t) {
    float m = r[0];
    m = fminf(m, __shfl_xor(m, 1));
    m = fminf(m, __shfl_xor(m, 2));
    m = fminf(m, __shfl_xor(m, 4));
    m = fminf(m, __shfl_xor(m, 8));
    m = fminf(m, __shfl_xor(m, 16));
    m = fminf(m, __shfl_xor(m, 32));
    unsigned long long who = __ballot(r[0] == m);
    int srcl = __ffsll(who) - 1;
    if (lane == srcl) {
#pragma unroll
      for (int z = 0; z < 7; ++z) r[z] = r[z + 1];
      r[7] = INF;
    }
    tau = m;
  }
  return tau;   // exact 20th smallest (INF if <20 candidates)
}

__device__ __forceinline__ void emit_hits(
    int i, bool valid, float d, float tau, int cid, int lane, int& cnt,
    int* __restrict__ knn_out)
{
  unsigned long long less = __ballot(valid && d < tau);
  unsigned long long eq   = __ballot(valid && d == tau);
  if (less) {
    if (valid && d < tau) {
      int pos = cnt + (int)__popcll(less & ((1ull << lane) - 1ull));
      if (pos < KNN_K) knn_out[i * KNN_K + pos] = cid;
    }
    cnt += (int)__popcll(less);
  }
  if (eq && cnt < KNN_K) {
    if (valid && d == tau) {
      int pos = cnt + (int)__popcll(eq & ((1ull << lane) - 1ull));
      if (pos < KNN_K) knn_out[i * KNN_K + pos] = cid;
    }
    cnt = min(KNN_K, cnt + (int)__popcll(eq));
  }
}

// ---------------- kNN: grid-pruned exact; full-scan fallback ----------------
__global__ __launch_bounds__(256) void knn_kernel(
    const float4* __restrict__ pos4, const float4* __restrict__ pos4s,
    const int* __restrict__ perm, const int* __restrict__ cellptr,
    int* __restrict__ knn_out)
{
  const int lane = threadIdx.x & 63, wave = threadIdx.x >> 6;
  const int wid = blockIdx.x * 4 + wave;
  const int i = perm[wid];                         // perm-ordered queries: L2 locality
  const float4 pi = pos4[i];
  const float INF = __builtin_inff();

  const int cx = min(15, max(0, (int)floorf((pi.x + 4.0f) * 2.0f)));
  const int cy = min(15, max(0, (int)floorf((pi.y + 4.0f) * 2.0f)));
  const int cz = min(15, max(0, (int)floorf((pi.z + 4.0f) * 2.0f)));
  const int x0 = max(cx - 1, 0), x1 = min(cx + 1, 15);
  const int y0 = max(cy - 1, 0), y1 = min(cy + 1, 15);
  const int z0 = max(cz - 1, 0), z1 = min(cz + 1, 15);

  float r[8];
#pragma unroll
  for (int q = 0; q < 8; ++q) r[q] = INF;

  // phase A: top-8 over the <=27-cell block (z-contiguous ranges)
  for (int X = x0; X <= x1; ++X)
    for (int Y = y0; Y <= y1; ++Y) {
      const int cb = (X << 8) | (Y << 4);
      const int s0 = cellptr[cb + z0], s1 = cellptr[cb + z1 + 1];
      for (int c0 = s0; c0 < s1; c0 += 64) {
        const int slot = c0 + lane;
        const int idx = min(slot, s1 - 1);
        const float4 s = pos4s[idx];
        const int nid = perm[idx];
        float d = knn_dist(pi, s);
        float k = (slot < s1 && nid != i) ? d : INF;
        insert8(r, k);
      }
    }
  float tau = merge_tau20(r, lane);

  // exactness margin: distance from query to scanned-region boundary
  float mx = INF, my = INF, mz = INF;
  if (x0 > 0)  mx = pi.x - (x0 * 0.5f - 4.0f);
  if (x1 < 15) mx = fminf(mx, ((x1 + 1) * 0.5f - 4.0f) - pi.x);
  if (y0 > 0)  my = pi.y - (y0 * 0.5f - 4.0f);
  if (y1 < 15) my = fminf(my, ((y1 + 1) * 0.5f - 4.0f) - pi.y);
  if (z0 > 0)  mz = pi.z - (z0 * 0.5f - 4.0f);
  if (z1 < 15) mz = fminf(mz, ((z1 + 1) * 0.5f - 4.0f) - pi.z);
  const float marg = fminf(mx, fminf(my, mz));

  if (tau < marg * marg) {
    // accepted: ball(sqrt(tau)) inside scanned region -> exact neighbor set
    int cnt = 0;
    for (int X = x0; X <= x1; ++X)
      for (int Y = y0; Y <= y1; ++Y) {
        const int cb = (X << 8) | (Y << 4);
        const int s0 = cellptr[cb + z0], s1 = cellptr[cb + z1 + 1];
        for (int c0 = s0; c0 < s1; c0 += 64) {
          const int slot = c0 + lane;
          const int idx = min(slot, s1 - 1);
          const float4 s = pos4s[idx];
          const int nid = perm[idx];
          float d = knn_dist(pi, s);
          bool valid = (slot < s1) && (nid != i);
          emit_hits(i, valid, d, tau, nid, lane, cnt, knn_out);
        }
      }
    return;
  }

  // fallback: round-6 full scan (exact, known-good)
#pragma unroll
  for (int q = 0; q < 8; ++q) r[q] = INF;
#pragma unroll 4
  for (int b = 0; b < NBATCH; ++b) {
    const int cid = b * 64 + lane;
    const float4 s = pos4[cid];
    float d = knn_dist(pi, s);                    // pad rows: +INF
    float k = (cid == i) ? INF : d;
    insert8(r, k);
  }
  tau = merge_tau20(r, lane);
  int cnt = 0;
  for (int b = 0; b < NBATCH; ++b) {
    const int cid = b * 64 + lane;
    const float4 s = pos4[cid];
    float d = knn_dist(pi, s);
    bool valid = (cid != i);
    emit_hits(i, valid, d, tau, cid, lane, cnt, knn_out);
  }
}

// ---------------- reverse-CSR build ----------------
__global__ __launch_bounds__(256) void count_kernel(
    const int* __restrict__ knn, int* __restrict__ counts)
{
  int e = blockIdx.x * 256 + threadIdx.x;
  if (e < NEDGE) atomicAdd(&counts[knn[e]], 1);
}

// node-degree exclusive scan (int4 loads; 250 threads x 40 exact)
__global__ __launch_bounds__(256) void scan_kernel(
    const int* __restrict__ counts, int* __restrict__ rptr)
{
  __shared__ int part[256];
  const int tid = threadIdx.x;
  const int base = tid * 40;                       // 250*40 = 10000 exact
  int s = 0;
  int cv[40];
  if (tid < 250) {
#pragma unroll
    for (int q = 0; q < 10; ++q) {
      int4 v = *(const int4*)&counts[base + q * 4];
      cv[q * 4 + 0] = v.x; cv[q * 4 + 1] = v.y;
      cv[q * 4 + 2] = v.z; cv[q * 4 + 3] = v.w;
      s += v.x + v.y + v.z + v.w;
    }
  }
  part[tid] = s;
  __syncthreads();
  for (int off = 1; off < 256; off <<= 1) {
    int add = (tid >= off) ? part[tid - off] : 0;
    __syncthreads();
    part[tid] += add;
    __syncthreads();
  }
  int run = part[tid] - s;                         // exclusive offset
  if (tid < 250) {
#pragma unroll
    for (int q = 0; q < 40; ++q) { rptr[base + q] = run; run += cv[q]; }
  }
  if (tid == 255) rptr[N_NODES] = run;
}

__global__ __launch_bounds__(256) void fill_kernel(
    const int* __restrict__ knn, const int* __restrict__ rptr,
    int* __restrict__ cursor, int* __restrict__ rsrc)
{
  int e = blockIdx.x * 256 + threadIdx.x;
  if (e < NEDGE) {
    int j = knn[e];
    int i = e / KNN_K;
    int p = atomicAdd(&cursor[j], 1);
    rsrc[rptr[j] + p] = i;
  }
}

// sort each reverse-adjacency list ascending (bitonic-64 per wave)
__global__ __launch_bounds__(256) void sort_kernel(
    const int* __restrict__ rptr, int* __restrict__ rsrc)
{
  const int lane = threadIdx.x & 63, wave = threadIdx.x >> 6;
  const int j = blockIdx.x * 4 + wave;
  const int s0 = rptr[j], s1 = rptr[j + 1], deg = s1 - s0;
  if (deg <= 64) {
    int v = (lane < deg) ? rsrc[s0 + lane] : 0x7FFFFFFF;
#pragma unroll
    for (int k = 2; k <= 64; k <<= 1) {
#pragma unroll
      for (int m = k >> 1; m > 0; m >>= 1) {
        int other = __shfl_xor(v, m);
        bool up = ((lane & k) == 0);
        bool lower = ((lane & m) == 0);
        v = (up == lower) ? min(v, other) : max(v, other);
      }
    }
    if (lane < deg) rsrc[s0 + lane] = v;
  } else if (lane == 0) {
    for (int a = s0 + 1; a < s1; ++a) {
      int v = rsrc[a];
      int b = a - 1;
      while (b >= s0 && rsrc[b] > v) { rsrc[b + 1] = rsrc[b]; --b; }
      rsrc[b + 1] = v;
    }
  }
}

// ---------------- prop: out[j] = scale2 * sum_{i in rev(j)} t[i] - prev[j] ----------------
// XCD-chunked spatial schedule (perm is cell-sorted -> L2-local gathers)
__global__ __launch_bounds__(256) void prop_kernel(
    const unsigned short* __restrict__ tin, const unsigned short* __restrict__ tprev,
    unsigned short* __restrict__ tout, const int* __restrict__ rptr,
    const int* __restrict__ rsrc, const int* __restrict__ perm, float scale2)
{
  const int wave = threadIdx.x >> 6, lane = threadIdx.x & 63;
  const int b = blockIdx.x;                        // grid 2504
  const int xcd = b & 7, qb = b >> 3;
  const int local = qb * 4 + wave;
  if (local >= NPX) return;                        // no barriers below: safe
  const int j = perm[xcd * NPX + local];
  const int s0 = rptr[j], s1 = rptr[j + 1];
  const size_t coff = (size_t)lane * 8;

  float a0[8], a1[8], a2[8], a3[8];
#pragma unroll
  for (int q = 0; q < 8; ++q) { a0[q] = 0.f; a1[q] = 0.f; a2[q] = 0.f; a3[q] = 0.f; }

  for (int base = s0; base < s1; base += 64) {
    const int clen = min(64, s1 - base);
    int myidx = (base + lane < s1) ? rsrc[base + lane] : 0;
    int t = 0;
    for (; t + 4 <= clen; t += 4) {
      int i0 = __shfl(myidx, t);
      int i1 = __shfl(myidx, t + 1);
      int i2 = __shfl(myidx, t + 2);
      int i3 = __shfl(myidx, t + 3);
      uint4 v0 = *(const uint4*)&tin[(size_t)i0 * 512 + coff];
      uint4 v1 = *(const uint4*)&tin[(size_t)i1 * 512 + coff];
      uint4 v2 = *(const uint4*)&tin[(size_t)i2 * 512 + coff];
      uint4 v3 = *(const uint4*)&tin[(size_t)i3 * 512 + coff];
      a0[0] += bf_lo(v0.x); a0[1] += bf_hi(v0.x); a0[2] += bf_lo(v0.y); a0[3] += bf_hi(v0.y);
      a0[4] += bf_lo(v0.z); a0[5] += bf_hi(v0.z); a0[6] += bf_lo(v0.w); a0[7] += bf_hi(v0.w);
      a1[0] += bf_lo(v1.x); a1[1] += bf_hi(v1.x); a1[2] += bf_lo(v1.y); a1[3] += bf_hi(v1.y);
      a1[4] += bf_lo(v1.z); a1[5] += bf_hi(v1.z); a1[6] += bf_lo(v1.w); a1[7] += bf_hi(v1.w);
      a2[0] += bf_lo(v2.x); a2[1] += bf_hi(v2.x); a2[2] += bf_lo(v2.y); a2[3] += bf_hi(v2.y);
      a2[4] += bf_lo(v2.z); a2[5] += bf_hi(v2.z); a2[6] += bf_lo(v2.w); a2[7] += bf_hi(v2.w);
      a3[0] += bf_lo(v3.x); a3[1] += bf_hi(v3.x); a3[2] += bf_lo(v3.y); a3[3] += bf_hi(v3.y);
      a3[4] += bf_lo(v3.z); a3[5] += bf_hi(v3.z); a3[6] += bf_lo(v3.w); a3[7] += bf_hi(v3.w);
    }
    for (; t < clen; ++t) {
      int i0 = __shfl(myidx, t);
      uint4 v0 = *(const uint4*)&tin[(size_t)i0 * 512 + coff];
      a0[0] += bf_lo(v0.x); a0[1] += bf_hi(v0.x); a0[2] += bf_lo(v0.y); a0[3] += bf_hi(v0.y);
      a0[4] += bf_lo(v0.z); a0[5] += bf_hi(v0.z); a0[6] += bf_lo(v0.w); a0[7] += bf_hi(v0.w);
    }
  }

  float pv[8] = {0.f, 0.f, 0.f, 0.f, 0.f, 0.f, 0.f, 0.f};
  if (tprev != nullptr) {
    uint4 p = *(const uint4*)&tprev[(size_t)j * 512 + coff];
    pv[0] = bf_lo(p.x); pv[1] = bf_hi(p.x);
    pv[2] = bf_lo(p.y); pv[3] = bf_hi(p.y);
    pv[4] = bf_lo(p.z); pv[5] = bf_hi(p.z);
    pv[6] = bf_lo(p.w); pv[7] = bf_hi(p.w);
  }
  unsigned short o16[8];
#pragma unroll
  for (int q = 0; q < 8; ++q) {
    float acc = (a0[q] + a1[q]) + (a2[q] + a3[q]);   // fixed tree, deterministic
    o16[q] = f2bf(scale2 * acc - pv[q]);
  }
  uint4 o;
  o.x = (unsigned int)o16[0] | ((unsigned int)o16[1] << 16);
  o.y = (unsigned int)o16[2] | ((unsigned int)o16[3] << 16);
  o.z = (unsigned int)o16[4] | ((unsigned int)o16[5] << 16);
  o.w = (unsigned int)o16[6] | ((unsigned int)o16[7] << 16);
  *(uint4*)&tout[(size_t)j * 512 + coff] = o;
}

// ---------------- GEMM: C[o][n] = sum_kc A[n][kc] * B[kc][o] + bias[o] ----------------
__global__ __launch_bounds__(256) void gemm_kernel(
    const unsigned short* __restrict__ A,
    const unsigned short* __restrict__ Bt,
    const float* __restrict__ bias,
    float* __restrict__ C)
{
  __shared__ __align__(16) char smem[64 * 132 * 4];   // 33792B: tiles(32KB) / epilogue(33KB)
  unsigned short* As = (unsigned short*)smem;         // [128][64] bf16
  unsigned short* Bs = As + 128 * 64;                 // [128 o][64 k] bf16
  float* eps = (float*)smem;                          // [64 o][132] f32

  const int tid = threadIdx.x;
  const int wave = tid >> 6, lane = tid & 63;
  const int l15 = lane & 15, hi = lane >> 4;
  const int wr = wave >> 1, wc = wave & 1;
  const int n0 = blockIdx.x * 128;
  const int o0 = blockIdx.y * 128;

  f32x4 acc[4][4];
#pragma unroll
  for (int a = 0; a < 4; ++a)
#pragma unroll
    for (int b = 0; b < 4; ++b) acc[a][b] = (f32x4){0.f, 0.f, 0.f, 0.f};

  for (int kt = 0; kt < 40; ++kt) {
    const int k0 = kt * 64;
    const int ko = k0 >> 9;
    const int c0 = k0 & 511;
    const unsigned short* Ab = A + (size_t)ko * ((size_t)N_NODES * 512);
#pragma unroll
    for (int q = 0; q < 4; ++q) {
      int idx = (wave * 4 + q) * 64 + lane;     // 16B unit id, 0..1023
      int r = idx >> 3, u = idx & 7;
      gll16(Ab + (size_t)(n0 + r) * 512 + c0 + u * 8, As + (size_t)(wave * 4 + q) * 512);
    }
#pragma unroll
    for (int q = 0; q < 4; ++q) {
      int idx = (wave * 4 + q) * 64 + lane;
      int r = idx >> 3, u = idx & 7;
      gll16(Bt + (size_t)(o0 + r) * 2560 + k0 + u * 8, Bs + (size_t)(wave * 4 + q) * 512);
    }
    __syncthreads();
#pragma unroll
    for (int kk = 0; kk < 2; ++kk) {
      bf16x8 af[4], bfr[4];
#pragma unroll
      for (int mi = 0; mi < 4; ++mi)
        af[mi] = *(const bf16x8*)(As + ((wr * 64 + mi * 16 + l15) * 64 + kk * 32 + hi * 8));
#pragma unroll
      for (int ni = 0; ni < 4; ++ni)
        bfr[ni] = *(const bf16x8*)(Bs + ((wc * 64 + ni * 16 + l15) * 64 + kk * 32 + hi * 8));
#pragma unroll
      for (int mi = 0; mi < 4; ++mi)
#pragma unroll
        for (int ni = 0; ni < 4; ++ni)
          acc[mi][ni] = __builtin_amdgcn_mfma_f32_16x16x32_bf16(af[mi], bfr[ni], acc[mi][ni], 0, 0, 0);
    }
    __syncthreads();
  }

  // epilogue: LDS-transposed coalesced store of C[o][n] + bias
#pragma unroll
  for (int h = 0; h < 2; ++h) {
    __syncthreads();
    if (wc == h) {
#pragma unroll
      for (int mi = 0; mi < 4; ++mi)
#pragma unroll
        for (int ni = 0; ni < 4; ++ni) {
          int o_l = ni * 16 + l15;                   // 0..63 within half
          int nb = wr * 64 + mi * 16 + hi * 4;       // 0..124, x4 aligned
          *(f32x4*)&eps[o_l * 132 + nb] = acc[mi][ni];
        }
    }
    __syncthreads();
#pragma unroll
    for (int q = 0; q < 8; ++q) {
      int unit = q * 256 + tid;                      // 2048 float4 units
      int o_l = unit >> 5, nu = unit & 31;
      int n = n0 + nu * 4;
      if (n < N_NODES) {
        int o = o0 + h * 64 + o_l;
        f32x4 v = *(const f32x4*)&eps[o_l * 132 + nu * 4];
        float bo = bias[o];
        v = v + bo;
        *(f32x4*)&C[(size_t)o * N_NODES + n] = v;
      }
    }
  }
}

extern "C" void kernel_launch(void* const* d_in, const int* in_sizes, int n_in,
                              void* d_out, int out_size, void* d_ws, size_t ws_size,
                              hipStream_t stream)
{
  const float* x        = (const float*)d_in[0];   // [512][10000]
  const float* position = (const float*)d_in[1];   // [10000][3]
  const float* theta    = (const float*)d_in[2];   // [5][512][512]
  const float* bias     = (const float*)d_in[3];   // [512]

  char* ws = (char*)d_ws;
  size_t off = 0;
  auto alloc = [&](size_t bytes) -> void* {
    void* p = ws + off;
    off = (off + bytes + 255) & ~(size_t)255;
    return p;
  };
  unsigned short* TxAll   = (unsigned short*)alloc(5ull * N_NODES * 512 * 2 + 131072); // +128-row pad
  unsigned short* thetabT = (unsigned short*)alloc(512ull * 2560 * 2);
  float4* pos4  = (float4*)alloc((size_t)POS4_PAD * 16);
  float4* pos4s = (float4*)alloc((size_t)N_NODES * 16);
  int* knn    = (int*)alloc((size_t)NEDGE * 4);
  int* rptr   = (int*)alloc((size_t)(N_NODES + 1) * 4);
  int* counts = (int*)alloc((size_t)N_NODES * 4);
  int* cursor = (int*)alloc((size_t)N_NODES * 4);
  int* rsrc   = (int*)alloc((size_t)NEDGE * 4);
  int* cellcnt = (int*)alloc((size_t)NCELL * 4);   // contiguous with cellcur:
  int* cellcur = (int*)alloc((size_t)NCELL * 4);   // one memset covers both
  int* cellptr = (int*)alloc((size_t)(NCELL + 1) * 4);
  int* cellid  = (int*)alloc((size_t)N_NODES * 4);
  int* perm    = (int*)alloc((size_t)N_NODES * 4);
  if (ws_size < off) return;   // insufficient scratch

  // theta [5][512][512] -> thetabT [o=512][kc=2560]
  transpose_f32_bf16<<<dim3(8, 8, 5), 256, 0, stream>>>(
      theta, thetabT, 512, 512, 2560, (size_t)512 * 512, 512);
  // x [512][10000] -> Tx0 [10000][512]
  transpose_f32_bf16<<<dim3(157, 8, 1), 256, 0, stream>>>(
      x, TxAll, 512, N_NODES, 512, 0, 0);

  hipMemsetAsync(cellcnt, 0, (size_t)((char*)cellptr - (char*)cellcnt), stream);
  pos4_kernel<<<40, 256, 0, stream>>>(position, pos4, counts, cursor, cellid, cellcnt);
  cellscan_kernel<<<1, 256, 0, stream>>>(cellcnt, cellptr);
  perm_kernel<<<40, 256, 0, stream>>>(cellid, cellptr, cellcur, perm, pos4, pos4s);

  knn_kernel<<<2500, 256, 0, stream>>>(pos4, pos4s, perm, cellptr, knn);

  count_kernel<<<(NEDGE + 255) / 256, 256, 0, stream>>>(knn, counts);
  scan_kernel<<<1, 256, 0, stream>>>(counts, rptr);
  fill_kernel<<<(NEDGE + 255) / 256, 256, 0, stream>>>(knn, rptr, cursor, rsrc);
  sort_kernel<<<2500, 256, 0, stream>>>(rptr, rsrc);

  unsigned short* Tx0 = TxAll;
  unsigned short* Tx1 = TxAll + 1ull * N_NODES * 512;
  unsigned short* Tx2 = TxAll + 2ull * N_NODES * 512;
  unsigned short* Tx3 = TxAll + 3ull * N_NODES * 512;
  unsigned short* Tx4 = TxAll + 4ull * N_NODES * 512;

  // Tx1 = prop(Tx0) = -0.05*sum ; Tx_k = 2*prop(Tx_{k-1}) - Tx_{k-2} = -0.10*sum - prev
  prop_kernel<<<2504, 256, 0, stream>>>(Tx0, nullptr, Tx1, rptr, rsrc, perm, -0.05f);
  prop_kernel<<<2504, 256, 0, stream>>>(Tx1, Tx0,     Tx2, rptr, rsrc, perm, -0.10f);
  prop_kernel<<<2504, 256, 0, stream>>>(Tx2, Tx1,     Tx3, rptr, rsrc, perm, -0.10f);
  prop_kernel<<<2504, 256, 0, stream>>>(Tx3, Tx2,     Tx4, rptr, rsrc, perm, -0.10f);

  gemm_kernel<<<dim3(79, 4), 256, 0, stream>>>(TxAll, thetabT, bias, (float*)d_out);
}